// Round 9
// baseline (309.502 us; speedup 1.0000x reference)
//
#include <hip/hip_runtime.h>
#include <cstddef>
#include <cstdint>

#define N_BATCH 16
#define C_IN    512
#define L       4096
#define KC      256
#define VC      512
#define NH      8
#define HK      32   // KC/NH
#define HV      64   // VC/NH

using f32x4 = __attribute__((ext_vector_type(4))) float;
using s16x8 = __attribute__((ext_vector_type(8))) short;

// round-to-nearest-even fp32 -> bf16 bits
static __device__ inline ushort f2bf(float f) {
  uint32_t u = __float_as_uint(f);
  uint32_t r = (u + 0x7FFFu + ((u >> 16) & 1u)) >> 16;
  return (ushort)r;
}
static __device__ inline float bf2f(ushort u) {
  return __uint_as_float((uint32_t)u << 16);
}

// ---------------------------------------------------------------------------
// Prep 1: bf16 weight matrix Wb[512][512] (rows 0..255 K, 256..511 Q) + bias
// ---------------------------------------------------------------------------
__global__ __launch_bounds__(256) void k_prep_w(
    const float* __restrict__ Wk, const float* __restrict__ bk,
    const float* __restrict__ Wq, const float* __restrict__ bq,
    ushort* __restrict__ Wb, float* __restrict__ bb)
{
  const int o = blockIdx.x;          // 512
  const float* src; const float* bsrc; int oo;
  if (o < 256) { src = Wk + (size_t)o * C_IN;         bsrc = bk; oo = o; }
  else         { src = Wq + (size_t)(o - 256) * C_IN; bsrc = bq; oo = o - 256; }
  const int t = threadIdx.x;
  Wb[(size_t)o * C_IN + t * 2]     = f2bf(src[t * 2]);
  Wb[(size_t)o * C_IN + t * 2 + 1] = f2bf(src[t * 2 + 1]);
  if (t == 0) bb[o] = bsrc[oo];
}

// ---------------------------------------------------------------------------
// Prep 2: x (n,512,4096) f32 -> xT (n,4096,512) bf16 (transposed)
//                            AND xb (n,512,4096) bf16 (straight cast)
// ---------------------------------------------------------------------------
__global__ __launch_bounds__(256) void k_prep_x(const float* __restrict__ x,
                                                ushort* __restrict__ xT,
                                                ushort* __restrict__ xb)
{
  __shared__ float t[64][65];
  const int n = blockIdx.z, cy = blockIdx.y, lx = blockIdx.x;
  const float* xp = x + ((size_t)n * C_IN + cy * 64) * L + (size_t)lx * 64;
  ushort* xbp = xb + ((size_t)n * C_IN + cy * 64) * L + (size_t)lx * 64;
  const int l4 = (threadIdx.x & 15) * 4;
  const int c0 = threadIdx.x >> 4;
  #pragma unroll
  for (int i = 0; i < 4; ++i) {
    int cc = c0 + i * 16;
    f32x4 v = *(const f32x4*)&xp[(size_t)cc * L + l4];
    t[cc][l4]     = v[0];
    t[cc][l4 + 1] = v[1];
    t[cc][l4 + 2] = v[2];
    t[cc][l4 + 3] = v[3];
    uint2 pk;
    pk.x = (uint32_t)f2bf(v[0]) | ((uint32_t)f2bf(v[1]) << 16);
    pk.y = (uint32_t)f2bf(v[2]) | ((uint32_t)f2bf(v[3]) << 16);
    *(uint2*)(xbp + (size_t)cc * L + l4) = pk;
  }
  __syncthreads();
  ushort* op = xT + ((size_t)n * L + lx * 64) * C_IN + cy * 64;
  const int cp = (threadIdx.x & 15) * 4;
  const int l0 = threadIdx.x >> 4;
  #pragma unroll
  for (int i = 0; i < 4; ++i) {
    int lr = l0 + i * 16;
    uint2 pk;
    pk.x = (uint32_t)f2bf(t[cp][lr])     | ((uint32_t)f2bf(t[cp + 1][lr]) << 16);
    pk.y = (uint32_t)f2bf(t[cp + 2][lr]) | ((uint32_t)f2bf(t[cp + 3][lr]) << 16);
    *(uint2*)(op + (size_t)lr * C_IN + cp) = pk;
  }
}

// ---------------------------------------------------------------------------
// Kernel 1: [K;Q] = Wb @ x + bias, bf16 MFMA, 256x256 tile, BK=64, 8 waves.
// Round-6 proven 2-phase dbuf structure (syncthreads loop + setprio).
// oy=0 -> K rows -> Kbuf[n][256][L]; oy=1 -> Q rows, fused channel softmax
// -> qT[n][l][256] (each head fully within one wr half).
// ---------------------------------------------------------------------------
#define QBM 256
#define QBN 256
#define QBK 64

__global__ __launch_bounds__(512) void k_kq_mfma(
    const ushort* __restrict__ Wb,   // [512][512] bf16
    const ushort* __restrict__ xT,   // [n][4096][512] bf16
    const float* __restrict__ bb,    // [512]
    ushort* __restrict__ Kbuf,       // [n][256][4096] bf16
    ushort* __restrict__ qT)         // [n][4096][256] bf16 (normalized Q^T)
{
  extern __shared__ __align__(16) char smem[];
  const int n  = blockIdx.z;
  const int oy = blockIdx.y;   // 0 = K rows, 1 = Q rows
  const int lx = blockIdx.x;   // 16 col tiles of 256
  const int tid  = threadIdx.x;
  const int wave = tid >> 6, lane = tid & 63;
  const int wr = wave >> 2, wc = wave & 3;   // 2 x 4

  f32x4 acc[8][4] = {};

  const ushort* gA = Wb + (size_t)(oy * QBM) * C_IN;
  const ushort* gB = xT + ((size_t)n * L + lx * QBN) * C_IN;

  const int srow = lane >> 3;
  const int sslotbase = lane & 7;

  #define QSTAGE(buf, k0)                                                        \
    {                                                                            \
      ushort* As_ = (ushort*)(smem + (buf) * 65536);                             \
      ushort* Bs_ = (ushort*)(smem + (buf) * 65536 + 32768);                     \
      _Pragma("unroll")                                                          \
      for (int i_ = 0; i_ < 4; ++i_) {                                           \
        int rbase_ = wave * 32 + i_ * 8;                                         \
        int row_ = rbase_ + srow;                                                \
        int ss_ = sslotbase ^ (row_ & 7);                                        \
        __builtin_amdgcn_global_load_lds(                                        \
            (const __attribute__((address_space(1))) uint32_t*)(gA + (size_t)row_ * C_IN + (k0) + ss_ * 8), \
            (__attribute__((address_space(3))) uint32_t*)(As_ + rbase_ * QBK),   \
            16, 0, 0);                                                           \
        __builtin_amdgcn_global_load_lds(                                        \
            (const __attribute__((address_space(1))) uint32_t*)(gB + (size_t)row_ * C_IN + (k0) + ss_ * 8), \
            (__attribute__((address_space(3))) uint32_t*)(Bs_ + rbase_ * QBK),   \
            16, 0, 0);                                                           \
      }                                                                          \
    }

  QSTAGE(0, 0)
  __syncthreads();

  const int nt = C_IN / QBK;   // 8
  for (int t = 0; t < nt; ++t) {
    if (t < nt - 1) QSTAGE((t + 1) & 1, (t + 1) * QBK)
    ushort* As = (ushort*)(smem + (t & 1) * 65536);
    ushort* Bs = (ushort*)(smem + (t & 1) * 65536 + 32768);
    __builtin_amdgcn_s_setprio(1);
    #pragma unroll
    for (int ks = 0; ks < 2; ++ks) {
      s16x8 af[8], bfr[4];
      #pragma unroll
      for (int m = 0; m < 8; ++m) {
        int row = wr * 128 + m * 16 + (lane & 15);
        int slot = (ks * 4 + (lane >> 4)) ^ (row & 7);
        af[m] = *(const s16x8*)&As[row * QBK + slot * 8];
      }
      #pragma unroll
      for (int nn = 0; nn < 4; ++nn) {
        int row = wc * 64 + nn * 16 + (lane & 15);
        int slot = (ks * 4 + (lane >> 4)) ^ (row & 7);
        bfr[nn] = *(const s16x8*)&Bs[row * QBK + slot * 8];
      }
      #pragma unroll
      for (int m = 0; m < 8; ++m)
        #pragma unroll
        for (int nn = 0; nn < 4; ++nn)
          acc[m][nn] = __builtin_amdgcn_mfma_f32_16x16x32_bf16(af[m], bfr[nn], acc[m][nn], 0, 0, 0);
    }
    __builtin_amdgcn_s_setprio(0);
    __syncthreads();
  }
  #undef QSTAGE

  if (oy == 0) {
    // K rows: wave-private 16x68 f32 LDS transpose -> uint2 bf16 stores.
    float* ep = (float*)smem + wave * (16 * 68);
    const int erow = lane >> 4;
    const int ecol = lane & 15;
    const float* bias = bb + wr * 128;
    ushort* outp = Kbuf + ((size_t)n * 256 + wr * 128) * L
                 + (size_t)lx * QBN + wc * 64;
    #pragma unroll
    for (int m = 0; m < 8; ++m) {
      #pragma unroll
      for (int nn = 0; nn < 4; ++nn)
        #pragma unroll
        for (int r = 0; r < 4; ++r)
          ep[(erow * 4 + r) * 68 + nn * 16 + ecol] = acc[m][nn][r];
      #pragma unroll
      for (int p = 0; p < 4; ++p) {
        int row = p * 4 + erow;
        f32x4 v = *(const f32x4*)&ep[row * 68 + ecol * 4];
        float bo = bias[m * 16 + row];
        uint2 pk;
        pk.x = (uint32_t)f2bf(v[0] + bo) | ((uint32_t)f2bf(v[1] + bo) << 16);
        pk.y = (uint32_t)f2bf(v[2] + bo) | ((uint32_t)f2bf(v[3] + bo) << 16);
        *(uint2*)&outp[(size_t)(m * 16 + row) * L + ecol * 4] = pk;
      }
    }
  } else {
    // Q rows: fused channel softmax (32 channels/head, head within wr half).
    const float* bias = bb + 256 + wr * 128;
    ushort* qbase = qT + (size_t)n * L * KC;
    const int g4 = (lane >> 4) * 4;
    #pragma unroll
    for (int hp = 0; hp < 4; ++hp) {
      const int m0 = 2 * hp, m1 = 2 * hp + 1;
      const float b0_0 = bias[m0 * 16 + g4 + 0], b0_1 = bias[m0 * 16 + g4 + 1];
      const float b0_2 = bias[m0 * 16 + g4 + 2], b0_3 = bias[m0 * 16 + g4 + 3];
      const float b1_0 = bias[m1 * 16 + g4 + 0], b1_1 = bias[m1 * 16 + g4 + 1];
      const float b1_2 = bias[m1 * 16 + g4 + 2], b1_3 = bias[m1 * 16 + g4 + 3];
      #pragma unroll
      for (int nn = 0; nn < 4; ++nn) {
        float v0[4], v1[4];
        v0[0] = acc[m0][nn][0] + b0_0; v0[1] = acc[m0][nn][1] + b0_1;
        v0[2] = acc[m0][nn][2] + b0_2; v0[3] = acc[m0][nn][3] + b0_3;
        v1[0] = acc[m1][nn][0] + b1_0; v1[1] = acc[m1][nn][1] + b1_1;
        v1[2] = acc[m1][nn][2] + b1_2; v1[3] = acc[m1][nn][3] + b1_3;
        float mx = fmaxf(fmaxf(fmaxf(v0[0], v0[1]), fmaxf(v0[2], v0[3])),
                         fmaxf(fmaxf(v1[0], v1[1]), fmaxf(v1[2], v1[3])));
        mx = fmaxf(mx, __shfl_xor(mx, 16));
        mx = fmaxf(mx, __shfl_xor(mx, 32));
        float e0[4], e1[4];
        float s = 0.f;
        #pragma unroll
        for (int r = 0; r < 4; ++r) { e0[r] = __expf(v0[r] - mx); s += e0[r]; }
        #pragma unroll
        for (int r = 0; r < 4; ++r) { e1[r] = __expf(v1[r] - mx); s += e1[r]; }
        s += __shfl_xor(s, 16);
        s += __shfl_xor(s, 32);
        float inv = 1.0f / s;
        int l = lx * QBN + wc * 64 + nn * 16 + (lane & 15);
        ushort* dst = qbase + (size_t)l * KC + wr * 128;
        uint2 p0, p1;
        p0.x = (uint32_t)f2bf(e0[0] * inv) | ((uint32_t)f2bf(e0[1] * inv) << 16);
        p0.y = (uint32_t)f2bf(e0[2] * inv) | ((uint32_t)f2bf(e0[3] * inv) << 16);
        p1.x = (uint32_t)f2bf(e1[0] * inv) | ((uint32_t)f2bf(e1[1] * inv) << 16);
        p1.y = (uint32_t)f2bf(e1[2] * inv) | ((uint32_t)f2bf(e1[3] * inv) << 16);
        *(uint2*)&dst[m0 * 16 + g4] = p0;
        *(uint2*)&dst[m1 * 16 + g4] = p1;
      }
    }
  }
}

// ---------------------------------------------------------------------------
// Reductions
// ---------------------------------------------------------------------------
__device__ inline float blockReduceMax(float v, float* red) {
  #pragma unroll
  for (int off = 32; off > 0; off >>= 1)
    v = fmaxf(v, __shfl_down(v, off, 64));
  int tid = threadIdx.x;
  if ((tid & 63) == 0) red[tid >> 6] = v;
  __syncthreads();
  return fmaxf(fmaxf(red[0], red[1]), fmaxf(red[2], red[3]));
}
__device__ inline float blockReduceSum(float v, float* red) {
  #pragma unroll
  for (int off = 32; off > 0; off >>= 1)
    v += __shfl_down(v, off, 64);
  int tid = threadIdx.x;
  if ((tid & 63) == 0) red[tid >> 6] = v;
  __syncthreads();
  return red[0] + red[1] + red[2] + red[3];
}

// ---------------------------------------------------------------------------
// Kernel 2: K softmax over L per (n,row); writes normalized Ksm bf16.
// ---------------------------------------------------------------------------
__global__ __launch_bounds__(256) void k_kstats2(const ushort* __restrict__ Kbuf,
                                                 ushort* __restrict__ Ksm)
{
  const int r = blockIdx.x;
  const int n = blockIdx.y;
  const ushort* row = Kbuf + ((size_t)n * 256 + r) * L;
  ushort* orow = Ksm + ((size_t)n * 256 + r) * L;
  __shared__ float red1[4];
  __shared__ float red2[4];
  const int tid = threadIdx.x;
  s16x8 a = *(const s16x8*)(row + tid * 16);
  s16x8 b = *(const s16x8*)(row + tid * 16 + 8);
  float v[16];
  #pragma unroll
  for (int j = 0; j < 8; ++j) { v[j] = bf2f((ushort)a[j]); v[8 + j] = bf2f((ushort)b[j]); }
  float m = -3.0e38f;
  #pragma unroll
  for (int j = 0; j < 16; ++j) m = fmaxf(m, v[j]);
  m = blockReduceMax(m, red1);
  float s = 0.f;
  #pragma unroll
  for (int j = 0; j < 16; ++j) s += __expf(v[j] - m);
  s = blockReduceSum(s, red2);
  float inv = 1.0f / s;
  s16x8 w0, w1;
  #pragma unroll
  for (int j = 0; j < 8; ++j) {
    w0[j] = (short)f2bf(__expf(v[j] - m) * inv);
    w1[j] = (short)f2bf(__expf(v[8 + j] - m) * inv);
  }
  *(s16x8*)(orow + tid * 16)     = w0;
  *(s16x8*)(orow + tid * 16 + 8) = w1;
}

// ---------------------------------------------------------------------------
// Kernel 3: G^T = Ksm @ xb^T.  Per batch: M=256(k), N=512(c), K-dim=L=4096
// split into 2 l-chunks of 2048.  128x128 tile, BK=32, 2-phase dbuf.
// Output partials Gp[n][2][256][512] f32.
// ---------------------------------------------------------------------------
#define GBK 32

__global__ __launch_bounds__(256) void k_G(
    const ushort* __restrict__ Ksm,  // [n][256][4096] bf16
    const ushort* __restrict__ xb,   // [n][512][4096] bf16
    float* __restrict__ Gp)          // [n][2][256][512] f32
{
  const int n  = blockIdx.z;
  const int cx = blockIdx.x;           // 4 c-tiles of 128
  const int ky = blockIdx.y >> 1;      // 2 k-tiles of 128
  const int lc = blockIdx.y & 1;       // 2 l-chunks of 2048
  const int tid  = threadIdx.x;
  const int wave = tid >> 6, lane = tid & 63;
  const int wr = wave >> 1, wc = wave & 1;

  __shared__ __align__(16) char smem[32768 + 17408];

  f32x4 acc[4][4] = {};

  const ushort* gA = Ksm + ((size_t)n * 256 + ky * 128) * L + lc * 2048;
  const ushort* gB = xb  + ((size_t)n * 512 + cx * 128) * L + lc * 2048;

  const int r0 = wave * 32;
  const int lrow = lane >> 2;

  #define GSTAGE(buf, k0)                                                        \
    {                                                                            \
      ushort* As_ = (ushort*)(smem + (buf) * 16384);                             \
      ushort* Bs_ = (ushort*)(smem + (buf) * 16384 + 8192);                      \
      _Pragma("unroll")                                                          \
      for (int i_ = 0; i_ < 2; ++i_) {                                           \
        int row_ = r0 + i_ * 16 + lrow;                                          \
        int ss_ = (lane & 3) ^ ((row_ >> 1) & 3);                                \
        __builtin_amdgcn_global_load_lds(                                        \
            (const __attribute__((address_space(1))) uint32_t*)(gA + (size_t)row_ * L + (k0) + ss_ * 8), \
            (__attribute__((address_space(3))) uint32_t*)(As_ + (r0 + i_ * 16) * GBK), \
            16, 0, 0);                                                           \
        __builtin_amdgcn_global_load_lds(                                        \
            (const __attribute__((address_space(1))) uint32_t*)(gB + (size_t)row_ * L + (k0) + ss_ * 8), \
            (__attribute__((address_space(3))) uint32_t*)(Bs_ + (r0 + i_ * 16) * GBK), \
            16, 0, 0);                                                           \
      }                                                                          \
    }

  GSTAGE(0, 0)
  __syncthreads();

  const int nt = 2048 / GBK;   // 64
  for (int t = 0; t < nt; ++t) {
    if (t < nt - 1) GSTAGE((t + 1) & 1, (t + 1) * GBK)
    ushort* As = (ushort*)(smem + (t & 1) * 16384);
    ushort* Bs = (ushort*)(smem + (t & 1) * 16384 + 8192);
    s16x8 af[4], bfr[4];
    #pragma unroll
    for (int m = 0; m < 4; ++m) {
      int row = wr * 64 + m * 16 + (lane & 15);
      int slot = (lane >> 4) ^ ((row >> 1) & 3);
      af[m] = *(const s16x8*)&As[row * GBK + slot * 8];
    }
    #pragma unroll
    for (int nn = 0; nn < 4; ++nn) {
      int row = wc * 64 + nn * 16 + (lane & 15);
      int slot = (lane >> 4) ^ ((row >> 1) & 3);
      bfr[nn] = *(const s16x8*)&Bs[row * GBK + slot * 8];
    }
    __builtin_amdgcn_s_setprio(1);
    #pragma unroll
    for (int m = 0; m < 4; ++m)
      #pragma unroll
      for (int nn = 0; nn < 4; ++nn)
        acc[m][nn] = __builtin_amdgcn_mfma_f32_16x16x32_bf16(af[m], bfr[nn], acc[m][nn], 0, 0, 0);
    __builtin_amdgcn_s_setprio(0);
    __syncthreads();
  }
  #undef GSTAGE

  // Epilogue: wave-private 16x68 f32 staging -> f32x4 stores.
  float* ep = (float*)(smem + 32768) + wave * (16 * 68);
  const int erow = lane >> 4;
  const int ecol = lane & 15;
  float* op = Gp + (((size_t)n * 2 + lc) * 256 + ky * 128 + wr * 64) * 512
            + cx * 128 + wc * 64;
  #pragma unroll
  for (int m = 0; m < 4; ++m) {
    #pragma unroll
    for (int nn = 0; nn < 4; ++nn)
      #pragma unroll
      for (int r = 0; r < 4; ++r)
        ep[(erow * 4 + r) * 68 + nn * 16 + ecol] = acc[m][nn][r];
    #pragma unroll
    for (int p = 0; p < 4; ++p) {
      int row = p * 4 + erow;
      f32x4 v = *(const f32x4*)&ep[row * 68 + ecol * 4];
      *(f32x4*)&op[(size_t)(m * 16 + row) * 512 + ecol * 4] = v;
    }
  }
}

// ---------------------------------------------------------------------------
// Kernel 4: per (n,h): ctx[v][k] = sum_c Wv[h*64+v][c]*G[h*32+k][c] + bv[v];
// then Mbuf[o][h*32+k] = sum_v We[o][h*64+v]*ctx[v][k]  (bf16).
// G = Gp chunk0 + chunk1.
// ---------------------------------------------------------------------------
__global__ __launch_bounds__(256) void k_m2(const float* __restrict__ Gp,
                                            const float* __restrict__ Wv,
                                            const float* __restrict__ bv,
                                            const float* __restrict__ We,
                                            ushort* __restrict__ Mbuf)
{
  const int h = blockIdx.x;   // 8
  const int n = blockIdx.y;   // 16
  const int tid = threadIdx.x;
  __shared__ float Gs[16][516];
  __shared__ float ctx[64][32];

  const float* g0 = Gp + ((size_t)n * 2 + 0) * 256 * 512 + (size_t)(h * HK) * 512;
  const float* g1 = Gp + ((size_t)n * 2 + 1) * 256 * 512 + (size_t)(h * HK) * 512;

  const int v  = tid >> 2;        // 0..63
  const int kg = tid & 3;         // 0..3
  const float* wvrow = Wv + (size_t)(h * HV + v) * C_IN;

  #pragma unroll
  for (int half = 0; half < 2; ++half) {
    // load 16 k-rows of G (chunk sum) into LDS
    #pragma unroll
    for (int i = 0; i < 32; ++i) {
      int e = tid + i * 256;              // 8192 = 16*512
      int kr = e >> 9, c = e & 511;
      int gk = half * 16 + kr;
      Gs[kr][c] = g0[(size_t)gk * 512 + c] + g1[(size_t)gk * 512 + c];
    }
    __syncthreads();
    float a0 = 0.f, a1 = 0.f, a2 = 0.f, a3 = 0.f;
    for (int c = 0; c < C_IN; ++c) {
      float w = wvrow[c];
      a0 += w * Gs[kg * 4 + 0][c];
      a1 += w * Gs[kg * 4 + 1][c];
      a2 += w * Gs[kg * 4 + 2][c];
      a3 += w * Gs[kg * 4 + 3][c];
    }
    float bvv = bv[h * HV + v];
    ctx[v][half * 16 + kg * 4 + 0] = a0 + bvv;
    ctx[v][half * 16 + kg * 4 + 1] = a1 + bvv;
    ctx[v][half * 16 + kg * 4 + 2] = a2 + bvv;
    ctx[v][half * 16 + kg * 4 + 3] = a3 + bvv;
    __syncthreads();
  }

  // M-fold (as old k_m)
  const int k  = tid & 31;
  const int og = tid >> 5;
  for (int j = 0; j < 64; ++j) {
    int o = og * 64 + j;
    const float* we = We + (size_t)o * VC + h * HV;
    float s = 0.f;
    #pragma unroll
    for (int vv = 0; vv < 64; ++vv) s += we[vv] * ctx[vv][k];
    Mbuf[((size_t)n * 512 + o) * KC + h * HK + k] = f2bf(s);
  }
}

// ---------------------------------------------------------------------------
// Kernel 5: out = x + be + M @ q_smT via MFMA (round-6 proven version).
// ---------------------------------------------------------------------------
#define BM 128
#define BN 128
#define BK 32

__global__ __launch_bounds__(256) void k_final_mfma(
    const ushort* __restrict__ Mb,   // [n][512][256] bf16
    const ushort* __restrict__ qT,   // [n][4096][256] bf16
    const float* __restrict__ x,
    const float* __restrict__ be,
    float* __restrict__ out)
{
  const int n  = blockIdx.z;
  const int oy = blockIdx.y;   // 4
  const int lx = blockIdx.x;   // 32
  const int tid  = threadIdx.x;
  const int wave = tid >> 6, lane = tid & 63;
  const int wr = wave >> 1, wc = wave & 1;

  __shared__ __align__(16) char smem[32768 + 17408];

  f32x4 acc[4][4] = {};

  const ushort* gA = Mb + ((size_t)n * 512 + oy * BM) * KC;
  const ushort* gB = qT + ((size_t)n * L + lx * BN) * KC;

  const int r0 = wave * 32;
  const int lrow = lane >> 2;

  #define FSTAGE(buf, k0)                                                        \
    {                                                                            \
      ushort* As_ = (ushort*)(smem + (buf) * 16384);                             \
      ushort* Bs_ = (ushort*)(smem + (buf) * 16384 + 8192);                      \
      _Pragma("unroll")                                                          \
      for (int i_ = 0; i_ < 2; ++i_) {                                           \
        int row_ = r0 + i_ * 16 + lrow;                                          \
        int ss_ = (lane & 3) ^ ((row_ >> 1) & 3);                                \
        __builtin_amdgcn_global_load_lds(                                        \
            (const __attribute__((address_space(1))) uint32_t*)(gA + (size_t)row_ * KC + (k0) + ss_ * 8), \
            (__attribute__((address_space(3))) uint32_t*)(As_ + (r0 + i_ * 16) * BK), \
            16, 0, 0);                                                           \
        __builtin_amdgcn_global_load_lds(                                        \
            (const __attribute__((address_space(1))) uint32_t*)(gB + (size_t)row_ * KC + (k0) + ss_ * 8), \
            (__attribute__((address_space(3))) uint32_t*)(Bs_ + (r0 + i_ * 16) * BK), \
            16, 0, 0);                                                           \
      }                                                                          \
    }

  FSTAGE(0, 0)
  __syncthreads();

  const int nt = KC / BK;   // 8
  for (int t = 0; t < nt; ++t) {
    if (t < nt - 1) FSTAGE((t + 1) & 1, (t + 1) * BK)
    ushort* As = (ushort*)(smem + (t & 1) * 16384);
    ushort* Bs = (ushort*)(smem + (t & 1) * 16384 + 8192);
    s16x8 af[4], bfr[4];
    #pragma unroll
    for (int m = 0; m < 4; ++m) {
      int row = wr * 64 + m * 16 + (lane & 15);
      int slot = (lane >> 4) ^ ((row >> 1) & 3);
      af[m] = *(const s16x8*)&As[row * BK + slot * 8];
    }
    #pragma unroll
    for (int nn = 0; nn < 4; ++nn) {
      int row = wc * 64 + nn * 16 + (lane & 15);
      int slot = (lane >> 4) ^ ((row >> 1) & 3);
      bfr[nn] = *(const s16x8*)&Bs[row * BK + slot * 8];
    }
    __builtin_amdgcn_s_setprio(1);
    #pragma unroll
    for (int m = 0; m < 4; ++m)
      #pragma unroll
      for (int nn = 0; nn < 4; ++nn)
        acc[m][nn] = __builtin_amdgcn_mfma_f32_16x16x32_bf16(af[m], bfr[nn], acc[m][nn], 0, 0, 0);
    __builtin_amdgcn_s_setprio(0);
    __syncthreads();
  }
  #undef FSTAGE

  float* ep = (float*)(smem + 32768) + wave * (16 * 68);
  const int erow = lane >> 4;
  const int ecol = lane & 15;
  const float* bias = be + oy * BM + wr * 64;
  const float* xp = x + ((size_t)n * 512 + oy * BM + wr * 64) * L
                  + (size_t)lx * BN + wc * 64;
  float* op = out + ((size_t)n * 512 + oy * BM + wr * 64) * L
            + (size_t)lx * BN + wc * 64;
  #pragma unroll
  for (int m = 0; m < 4; ++m) {
    #pragma unroll
    for (int nn = 0; nn < 4; ++nn)
      #pragma unroll
      for (int r = 0; r < 4; ++r)
        ep[(erow * 4 + r) * 68 + nn * 16 + ecol] = acc[m][nn][r];
    #pragma unroll
    for (int p = 0; p < 4; ++p) {
      int row = p * 4 + erow;
      f32x4 v = *(const f32x4*)&ep[row * 68 + ecol * 4];
      float bo = bias[m * 16 + row];
      f32x4 xv = *(const f32x4*)&xp[(size_t)(m * 16 + row) * L + ecol * 4];
      v = v + xv + bo;
      *(f32x4*)&op[(size_t)(m * 16 + row) * L + ecol * 4] = v;
    }
  }
}

// ---------------------------------------------------------------------------
extern "C" void kernel_launch(void* const* d_in, const int* in_sizes, int n_in,
                              void* d_out, int out_size, void* d_ws, size_t ws_size,
                              hipStream_t stream)
{
  const float* x  = (const float*)d_in[0];
  const float* Wk = (const float*)d_in[1];
  const float* bk = (const float*)d_in[2];
  const float* Wq = (const float*)d_in[3];
  const float* bq = (const float*)d_in[4];
  const float* Wv = (const float*)d_in[5];
  const float* bv = (const float*)d_in[6];
  const float* We = (const float*)d_in[7];
  const float* be = (const float*)d_in[8];
  float* out = (float*)d_out;

  char* ws = (char*)d_ws;
  size_t off = 0;
  ushort* Kbuf = (ushort*)(ws + off); off += (size_t)N_BATCH * 256 * L * 2;   // 33.6 MB
  ushort* Ksm  = (ushort*)(ws + off); off += (size_t)N_BATCH * 256 * L * 2;   // 33.6 MB
  ushort* xT   = (ushort*)(ws + off); off += (size_t)N_BATCH * L * C_IN * 2;  // 67.1 MB
  ushort* xb   = (ushort*)(ws + off); off += (size_t)N_BATCH * C_IN * L * 2;  // 67.1 MB
  ushort* Wb   = (ushort*)(ws + off); off += (size_t)512 * C_IN * 2;          // 0.5 MB
  float*  bb   = (float*)(ws + off);  off += (size_t)512 * 4;
  ushort* qT   = (ushort*)(ws + off); off += (size_t)N_BATCH * L * KC * 2;    // 33.6 MB
  float*  Gp   = (float*)(ws + off);  off += (size_t)N_BATCH * 2 * 256 * 512 * 4; // 16.8 MB
  ushort* Mbuf = (ushort*)(ws + off); off += (size_t)N_BATCH * 512 * KC * 2;  // 4.2 MB

  (void)hipFuncSetAttribute((const void*)k_kq_mfma,
                            hipFuncAttributeMaxDynamicSharedMemorySize, 131072);

  k_prep_w<<<dim3(512), 256, 0, stream>>>(Wk, bk, Wq, bq, Wb, bb);
  k_prep_x<<<dim3(64, 8, N_BATCH), 256, 0, stream>>>(x, xT, xb);
  k_kq_mfma<<<dim3(16, 2, N_BATCH), 512, 131072, stream>>>(Wb, xT, bb, Kbuf, qT);
  k_kstats2<<<dim3(KC, N_BATCH), 256, 0, stream>>>(Kbuf, Ksm);
  k_G<<<dim3(4, 4, N_BATCH), 256, 0, stream>>>(Ksm, xb, Gp);
  k_m2<<<dim3(NH, N_BATCH), 256, 0, stream>>>(Gp, Wv, bv, We, Mbuf);
  k_final_mfma<<<dim3(32, 4, N_BATCH), 256, 0, stream>>>(Mbuf, qT, x, be, out);
}

// Round 10
// 291.501 us; speedup vs baseline: 1.0618x; 1.0618x over previous
//
#include <hip/hip_runtime.h>
#include <cstddef>
#include <cstdint>

#define N_BATCH 16
#define C_IN    512
#define L       4096
#define KC      256
#define VC      512
#define NH      8
#define HK      32   // KC/NH
#define HV      64   // VC/NH

using f32x4 = __attribute__((ext_vector_type(4))) float;
using s16x8 = __attribute__((ext_vector_type(8))) short;

// round-to-nearest-even fp32 -> bf16 bits
static __device__ inline ushort f2bf(float f) {
  uint32_t u = __float_as_uint(f);
  uint32_t r = (u + 0x7FFFu + ((u >> 16) & 1u)) >> 16;
  return (ushort)r;
}
static __device__ inline float bf2f(ushort u) {
  return __uint_as_float((uint32_t)u << 16);
}

// ---------------------------------------------------------------------------
// Prep 1: bf16 weight matrix Wb[512][512] (rows 0..255 K, 256..511 Q) + bias
// ---------------------------------------------------------------------------
__global__ __launch_bounds__(256) void k_prep_w(
    const float* __restrict__ Wk, const float* __restrict__ bk,
    const float* __restrict__ Wq, const float* __restrict__ bq,
    ushort* __restrict__ Wb, float* __restrict__ bb)
{
  const int o = blockIdx.x;          // 512
  const float* src; const float* bsrc; int oo;
  if (o < 256) { src = Wk + (size_t)o * C_IN;         bsrc = bk; oo = o; }
  else         { src = Wq + (size_t)(o - 256) * C_IN; bsrc = bq; oo = o - 256; }
  const int t = threadIdx.x;
  Wb[(size_t)o * C_IN + t * 2]     = f2bf(src[t * 2]);
  Wb[(size_t)o * C_IN + t * 2 + 1] = f2bf(src[t * 2 + 1]);
  if (t == 0) bb[o] = bsrc[oo];
}

// ---------------------------------------------------------------------------
// Prep 2: transpose+cast x (n,512,4096) f32 -> xT (n,4096,512) bf16
// ---------------------------------------------------------------------------
__global__ __launch_bounds__(256) void k_prep_x(const float* __restrict__ x,
                                                ushort* __restrict__ xT)
{
  __shared__ float t[64][65];
  const int n = blockIdx.z, cy = blockIdx.y, lx = blockIdx.x;
  const float* xp = x + ((size_t)n * C_IN + cy * 64) * L + (size_t)lx * 64;
  const int l4 = (threadIdx.x & 15) * 4;
  const int c0 = threadIdx.x >> 4;
  #pragma unroll
  for (int i = 0; i < 4; ++i) {
    int cc = c0 + i * 16;
    f32x4 v = *(const f32x4*)&xp[(size_t)cc * L + l4];
    t[cc][l4]     = v[0];
    t[cc][l4 + 1] = v[1];
    t[cc][l4 + 2] = v[2];
    t[cc][l4 + 3] = v[3];
  }
  __syncthreads();
  ushort* op = xT + ((size_t)n * L + lx * 64) * C_IN + cy * 64;
  const int cp = (threadIdx.x & 15) * 4;
  const int l0 = threadIdx.x >> 4;
  #pragma unroll
  for (int i = 0; i < 4; ++i) {
    int lr = l0 + i * 16;
    uint2 pk;
    pk.x = (uint32_t)f2bf(t[cp][lr])     | ((uint32_t)f2bf(t[cp + 1][lr]) << 16);
    pk.y = (uint32_t)f2bf(t[cp + 2][lr]) | ((uint32_t)f2bf(t[cp + 3][lr]) << 16);
    *(uint2*)(op + (size_t)lr * C_IN + cp) = pk;
  }
}

// ---------------------------------------------------------------------------
// Kernel 1: [K;Q] = Wb @ x + bias, bf16 MFMA, 256x256 tile, BK=64, 8 waves.
// Round-6 proven 2-phase dbuf structure.  oy=0 -> Kbuf; oy=1 -> fused
// channel softmax -> qT.
// ---------------------------------------------------------------------------
#define QBM 256
#define QBN 256
#define QBK 64

__global__ __launch_bounds__(512) void k_kq_mfma(
    const ushort* __restrict__ Wb,   // [512][512] bf16
    const ushort* __restrict__ xT,   // [n][4096][512] bf16
    const float* __restrict__ bb,    // [512]
    ushort* __restrict__ Kbuf,       // [n][256][4096] bf16
    ushort* __restrict__ qT)         // [n][4096][256] bf16 (normalized Q^T)
{
  extern __shared__ __align__(16) char smem[];
  const int n  = blockIdx.z;
  const int oy = blockIdx.y;   // 0 = K rows, 1 = Q rows
  const int lx = blockIdx.x;   // 16 col tiles of 256
  const int tid  = threadIdx.x;
  const int wave = tid >> 6, lane = tid & 63;
  const int wr = wave >> 2, wc = wave & 3;   // 2 x 4

  f32x4 acc[8][4] = {};

  const ushort* gA = Wb + (size_t)(oy * QBM) * C_IN;
  const ushort* gB = xT + ((size_t)n * L + lx * QBN) * C_IN;

  const int srow = lane >> 3;
  const int sslotbase = lane & 7;

  #define QSTAGE(buf, k0)                                                        \
    {                                                                            \
      ushort* As_ = (ushort*)(smem + (buf) * 65536);                             \
      ushort* Bs_ = (ushort*)(smem + (buf) * 65536 + 32768);                     \
      _Pragma("unroll")                                                          \
      for (int i_ = 0; i_ < 4; ++i_) {                                           \
        int rbase_ = wave * 32 + i_ * 8;                                         \
        int row_ = rbase_ + srow;                                                \
        int ss_ = sslotbase ^ (row_ & 7);                                        \
        __builtin_amdgcn_global_load_lds(                                        \
            (const __attribute__((address_space(1))) uint32_t*)(gA + (size_t)row_ * C_IN + (k0) + ss_ * 8), \
            (__attribute__((address_space(3))) uint32_t*)(As_ + rbase_ * QBK),   \
            16, 0, 0);                                                           \
        __builtin_amdgcn_global_load_lds(                                        \
            (const __attribute__((address_space(1))) uint32_t*)(gB + (size_t)row_ * C_IN + (k0) + ss_ * 8), \
            (__attribute__((address_space(3))) uint32_t*)(Bs_ + rbase_ * QBK),   \
            16, 0, 0);                                                           \
      }                                                                          \
    }

  QSTAGE(0, 0)
  __syncthreads();

  const int nt = C_IN / QBK;   // 8
  for (int t = 0; t < nt; ++t) {
    if (t < nt - 1) QSTAGE((t + 1) & 1, (t + 1) * QBK)
    ushort* As = (ushort*)(smem + (t & 1) * 65536);
    ushort* Bs = (ushort*)(smem + (t & 1) * 65536 + 32768);
    __builtin_amdgcn_s_setprio(1);
    #pragma unroll
    for (int ks = 0; ks < 2; ++ks) {
      s16x8 af[8], bfr[4];
      #pragma unroll
      for (int m = 0; m < 8; ++m) {
        int row = wr * 128 + m * 16 + (lane & 15);
        int slot = (ks * 4 + (lane >> 4)) ^ (row & 7);
        af[m] = *(const s16x8*)&As[row * QBK + slot * 8];
      }
      #pragma unroll
      for (int nn = 0; nn < 4; ++nn) {
        int row = wc * 64 + nn * 16 + (lane & 15);
        int slot = (ks * 4 + (lane >> 4)) ^ (row & 7);
        bfr[nn] = *(const s16x8*)&Bs[row * QBK + slot * 8];
      }
      #pragma unroll
      for (int m = 0; m < 8; ++m)
        #pragma unroll
        for (int nn = 0; nn < 4; ++nn)
          acc[m][nn] = __builtin_amdgcn_mfma_f32_16x16x32_bf16(af[m], bfr[nn], acc[m][nn], 0, 0, 0);
    }
    __builtin_amdgcn_s_setprio(0);
    __syncthreads();
  }
  #undef QSTAGE

  if (oy == 0) {
    float* ep = (float*)smem + wave * (16 * 68);
    const int erow = lane >> 4;
    const int ecol = lane & 15;
    const float* bias = bb + wr * 128;
    ushort* outp = Kbuf + ((size_t)n * 256 + wr * 128) * L
                 + (size_t)lx * QBN + wc * 64;
    #pragma unroll
    for (int m = 0; m < 8; ++m) {
      #pragma unroll
      for (int nn = 0; nn < 4; ++nn)
        #pragma unroll
        for (int r = 0; r < 4; ++r)
          ep[(erow * 4 + r) * 68 + nn * 16 + ecol] = acc[m][nn][r];
      #pragma unroll
      for (int p = 0; p < 4; ++p) {
        int row = p * 4 + erow;
        f32x4 v = *(const f32x4*)&ep[row * 68 + ecol * 4];
        float bo = bias[m * 16 + row];
        uint2 pk;
        pk.x = (uint32_t)f2bf(v[0] + bo) | ((uint32_t)f2bf(v[1] + bo) << 16);
        pk.y = (uint32_t)f2bf(v[2] + bo) | ((uint32_t)f2bf(v[3] + bo) << 16);
        *(uint2*)&outp[(size_t)(m * 16 + row) * L + ecol * 4] = pk;
      }
    }
  } else {
    const float* bias = bb + 256 + wr * 128;
    ushort* qbase = qT + (size_t)n * L * KC;
    const int g4 = (lane >> 4) * 4;
    #pragma unroll
    for (int hp = 0; hp < 4; ++hp) {
      const int m0 = 2 * hp, m1 = 2 * hp + 1;
      const float b0_0 = bias[m0 * 16 + g4 + 0], b0_1 = bias[m0 * 16 + g4 + 1];
      const float b0_2 = bias[m0 * 16 + g4 + 2], b0_3 = bias[m0 * 16 + g4 + 3];
      const float b1_0 = bias[m1 * 16 + g4 + 0], b1_1 = bias[m1 * 16 + g4 + 1];
      const float b1_2 = bias[m1 * 16 + g4 + 2], b1_3 = bias[m1 * 16 + g4 + 3];
      #pragma unroll
      for (int nn = 0; nn < 4; ++nn) {
        float v0[4], v1[4];
        v0[0] = acc[m0][nn][0] + b0_0; v0[1] = acc[m0][nn][1] + b0_1;
        v0[2] = acc[m0][nn][2] + b0_2; v0[3] = acc[m0][nn][3] + b0_3;
        v1[0] = acc[m1][nn][0] + b1_0; v1[1] = acc[m1][nn][1] + b1_1;
        v1[2] = acc[m1][nn][2] + b1_2; v1[3] = acc[m1][nn][3] + b1_3;
        float mx = fmaxf(fmaxf(fmaxf(v0[0], v0[1]), fmaxf(v0[2], v0[3])),
                         fmaxf(fmaxf(v1[0], v1[1]), fmaxf(v1[2], v1[3])));
        mx = fmaxf(mx, __shfl_xor(mx, 16));
        mx = fmaxf(mx, __shfl_xor(mx, 32));
        float e0[4], e1[4];
        float s = 0.f;
        #pragma unroll
        for (int r = 0; r < 4; ++r) { e0[r] = __expf(v0[r] - mx); s += e0[r]; }
        #pragma unroll
        for (int r = 0; r < 4; ++r) { e1[r] = __expf(v1[r] - mx); s += e1[r]; }
        s += __shfl_xor(s, 16);
        s += __shfl_xor(s, 32);
        float inv = 1.0f / s;
        int l = lx * QBN + wc * 64 + nn * 16 + (lane & 15);
        ushort* dst = qbase + (size_t)l * KC + wr * 128;
        uint2 p0, p1;
        p0.x = (uint32_t)f2bf(e0[0] * inv) | ((uint32_t)f2bf(e0[1] * inv) << 16);
        p0.y = (uint32_t)f2bf(e0[2] * inv) | ((uint32_t)f2bf(e0[3] * inv) << 16);
        p1.x = (uint32_t)f2bf(e1[0] * inv) | ((uint32_t)f2bf(e1[1] * inv) << 16);
        p1.y = (uint32_t)f2bf(e1[2] * inv) | ((uint32_t)f2bf(e1[3] * inv) << 16);
        *(uint2*)&dst[m0 * 16 + g4] = p0;
        *(uint2*)&dst[m1 * 16 + g4] = p1;
      }
    }
  }
}

// ---------------------------------------------------------------------------
// Reductions
// ---------------------------------------------------------------------------
__device__ inline float blockReduceMax(float v, float* red) {
  #pragma unroll
  for (int off = 32; off > 0; off >>= 1)
    v = fmaxf(v, __shfl_down(v, off, 64));
  int tid = threadIdx.x;
  if ((tid & 63) == 0) red[tid >> 6] = v;
  __syncthreads();
  return fmaxf(fmaxf(red[0], red[1]), fmaxf(red[2], red[3]));
}
__device__ inline float blockReduceSum(float v, float* red) {
  #pragma unroll
  for (int off = 32; off > 0; off >>= 1)
    v += __shfl_down(v, off, 64);
  int tid = threadIdx.x;
  if ((tid & 63) == 0) red[tid >> 6] = v;
  __syncthreads();
  return red[0] + red[1] + red[2] + red[3];
}

// ---------------------------------------------------------------------------
// Kernel 2: K softmax over L per (n,row); writes normalized Ksm bf16.
// ---------------------------------------------------------------------------
__global__ __launch_bounds__(256) void k_kstats2(const ushort* __restrict__ Kbuf,
                                                 ushort* __restrict__ Ksm)
{
  const int r = blockIdx.x;
  const int n = blockIdx.y;
  const ushort* row = Kbuf + ((size_t)n * 256 + r) * L;
  ushort* orow = Ksm + ((size_t)n * 256 + r) * L;
  __shared__ float red1[4];
  __shared__ float red2[4];
  const int tid = threadIdx.x;
  s16x8 a = *(const s16x8*)(row + tid * 16);
  s16x8 b = *(const s16x8*)(row + tid * 16 + 8);
  float v[16];
  #pragma unroll
  for (int j = 0; j < 8; ++j) { v[j] = bf2f((ushort)a[j]); v[8 + j] = bf2f((ushort)b[j]); }
  float m = -3.0e38f;
  #pragma unroll
  for (int j = 0; j < 16; ++j) m = fmaxf(m, v[j]);
  m = blockReduceMax(m, red1);
  float s = 0.f;
  #pragma unroll
  for (int j = 0; j < 16; ++j) s += __expf(v[j] - m);
  s = blockReduceSum(s, red2);
  float inv = 1.0f / s;
  s16x8 w0, w1;
  #pragma unroll
  for (int j = 0; j < 8; ++j) {
    w0[j] = (short)f2bf(__expf(v[j] - m) * inv);
    w1[j] = (short)f2bf(__expf(v[8 + j] - m) * inv);
  }
  *(s16x8*)(orow + tid * 16)     = w0;
  *(s16x8*)(orow + tid * 16 + 8) = w1;
}

// ---------------------------------------------------------------------------
// Kernel 3: G[c][k] = sum_l x[c,l] * Ksm[k,l]  (per n, partial over l-chunk).
// A = x f32 reg-staged (T14 split: load early, cvt+ds_write after compute);
// B = Ksm via global_load_lds.  M=128(c-tile), N=256(k), BK=64, 8 waves
// (2M x 4N), 2-phase dbuf (2 x 48 KB dynamic LDS).
// Gp[n][lc=4][512][256] f32 partials.
// ---------------------------------------------------------------------------
#define GBK 64

__global__ __launch_bounds__(512) void k_G(
    const float* __restrict__ x,     // [n][512][4096] f32
    const ushort* __restrict__ Ksm,  // [n][256][4096] bf16
    float* __restrict__ Gp)          // [n][4][512][256] f32
{
  extern __shared__ __align__(16) char smem[];
  const int cm = blockIdx.x;   // 4 c-tiles of 128
  const int lc = blockIdx.y;   // 4 l-chunks of 1024
  const int n  = blockIdx.z;
  const int tid  = threadIdx.x;
  const int wave = tid >> 6, lane = tid & 63;
  const int wr = wave >> 2, wc = wave & 3;   // 2 x 4

  f32x4 acc[4][4] = {};

  const float*  gx = x   + ((size_t)n * C_IN + cm * 128) * L + lc * 1024;
  const ushort* gK = Ksm + (size_t)n * 256 * L + lc * 1024;

  const int arow = tid >> 2;          // 0..127 (c row within tile)
  const int aseg = (tid & 3) * 2;     // this thread's 2 segs of 8 l-elems

  // B stage: Ksm rows 256 x 64 via global_load_lds (pre-swizzled source)
  #define GSTAGEB(buf, k0)                                                       \
    {                                                                            \
      ushort* Bs_ = (ushort*)(smem + (buf) * 49152 + 16384);                     \
      _Pragma("unroll")                                                          \
      for (int i_ = 0; i_ < 4; ++i_) {                                           \
        int rbase_ = wave * 32 + i_ * 8;                                         \
        int row_ = rbase_ + (lane >> 3);                                         \
        int ss_ = (lane & 7) ^ (row_ & 7);                                       \
        __builtin_amdgcn_global_load_lds(                                        \
            (const __attribute__((address_space(1))) uint32_t*)(gK + (size_t)row_ * L + (k0) + ss_ * 8), \
            (__attribute__((address_space(3))) uint32_t*)(Bs_ + rbase_ * GBK),   \
            16, 0, 0);                                                           \
      }                                                                          \
    }

  // A load (issue early): 16 f32 = 4 x f32x4
  #define GLOADA(k0)                                                             \
    a0 = *(const f32x4*)&gx[(size_t)arow * L + (k0) + aseg * 8];                 \
    a1 = *(const f32x4*)&gx[(size_t)arow * L + (k0) + aseg * 8 + 4];             \
    a2 = *(const f32x4*)&gx[(size_t)arow * L + (k0) + aseg * 8 + 8];             \
    a3 = *(const f32x4*)&gx[(size_t)arow * L + (k0) + aseg * 8 + 12];

  // A write (late): cvt to bf16, swizzled ds_write_b128 x2
  #define GWRITEA(buf)                                                           \
    {                                                                            \
      ushort* As_ = (ushort*)(smem + (buf) * 49152);                             \
      s16x8 w0_, w1_;                                                            \
      _Pragma("unroll")                                                          \
      for (int j_ = 0; j_ < 4; ++j_) {                                           \
        w0_[j_]     = (short)f2bf(a0[j_]);                                       \
        w0_[j_ + 4] = (short)f2bf(a1[j_]);                                       \
        w1_[j_]     = (short)f2bf(a2[j_]);                                       \
        w1_[j_ + 4] = (short)f2bf(a3[j_]);                                       \
      }                                                                          \
      *(s16x8*)&As_[arow * GBK + ((aseg)     ^ (arow & 7)) * 8] = w0_;           \
      *(s16x8*)&As_[arow * GBK + ((aseg + 1) ^ (arow & 7)) * 8] = w1_;           \
    }

  f32x4 a0, a1, a2, a3;

  // prologue: tile 0
  GLOADA(0)
  GSTAGEB(0, 0)
  GWRITEA(0)
  __syncthreads();

  const int nt = 1024 / GBK;   // 16
  for (int t = 0; t < nt; ++t) {
    const int cb = t & 1, nb = cb ^ 1;
    if (t < nt - 1) {
      GLOADA((t + 1) * GBK)        // f32 loads in flight during compute
      GSTAGEB(nb, (t + 1) * GBK)   // async DMA into next buffer
    }
    ushort* As = (ushort*)(smem + cb * 49152);
    ushort* Bs = (ushort*)(smem + cb * 49152 + 16384);
    __builtin_amdgcn_s_setprio(1);
    #pragma unroll
    for (int ks = 0; ks < 2; ++ks) {
      s16x8 af[4], bfr[4];
      #pragma unroll
      for (int m = 0; m < 4; ++m) {
        int row = wr * 64 + m * 16 + (lane & 15);
        int slot = (ks * 4 + (lane >> 4)) ^ (row & 7);
        af[m] = *(const s16x8*)&As[row * GBK + slot * 8];
      }
      #pragma unroll
      for (int nn = 0; nn < 4; ++nn) {
        int row = wc * 64 + nn * 16 + (lane & 15);
        int slot = (ks * 4 + (lane >> 4)) ^ (row & 7);
        bfr[nn] = *(const s16x8*)&Bs[row * GBK + slot * 8];
      }
      #pragma unroll
      for (int m = 0; m < 4; ++m)
        #pragma unroll
        for (int nn = 0; nn < 4; ++nn)
          acc[m][nn] = __builtin_amdgcn_mfma_f32_16x16x32_bf16(af[m], bfr[nn], acc[m][nn], 0, 0, 0);
    }
    __builtin_amdgcn_s_setprio(0);
    if (t < nt - 1) GWRITEA(nb)    // vmcnt wait lands here, after compute
    __syncthreads();
  }
  #undef GSTAGEB
  #undef GLOADA
  #undef GWRITEA

  // Epilogue: wave-private 16x68 f32 staging -> f32x4 stores.
  float* ep = (float*)smem + wave * (16 * 68);
  const int erow = lane >> 4;
  const int ecol = lane & 15;
  float* op = Gp + (((size_t)n * 4 + lc) * 512 + cm * 128 + wr * 64) * 256 + wc * 64;
  #pragma unroll
  for (int m = 0; m < 4; ++m) {
    #pragma unroll
    for (int nn = 0; nn < 4; ++nn)
      #pragma unroll
      for (int r = 0; r < 4; ++r)
        ep[(erow * 4 + r) * 68 + nn * 16 + ecol] = acc[m][nn][r];
    #pragma unroll
    for (int p = 0; p < 4; ++p) {
      int row16 = p * 4 + erow;
      f32x4 v = *(const f32x4*)&ep[row16 * 68 + ecol * 4];
      *(f32x4*)&op[(size_t)(m * 16 + row16) * 256 + ecol * 4] = v;
    }
  }
}

// ---------------------------------------------------------------------------
// Kernel 4: per (n,h): ctx[v][k] = sum_c Wv[h*64+v][c]*G[c][h*32+k] + bv[v];
// then Mbuf[o][h*32+k] = sum_v We[o][h*64+v]*ctx[v][k]  (bf16).
// G = sum over 4 lc partials; staged in two 256-c halves.
// ---------------------------------------------------------------------------
__global__ __launch_bounds__(256) void k_m2(const float* __restrict__ Gp,
                                            const float* __restrict__ Wv,
                                            const float* __restrict__ bv,
                                            const float* __restrict__ We,
                                            ushort* __restrict__ Mbuf)
{
  const int h = blockIdx.x;   // 8
  const int n = blockIdx.y;   // 16
  const int tid = threadIdx.x;
  __shared__ float Gs[256][36];   // pad 36: 144B rows, 16B-aligned f32x4
  __shared__ float ctx[64][32];

  const int v  = tid >> 2;        // 0..63
  const int kb = (tid & 3) * 8;   // 0,8,16,24
  float a[8] = {0.f, 0.f, 0.f, 0.f, 0.f, 0.f, 0.f, 0.f};

  #pragma unroll
  for (int hh = 0; hh < 2; ++hh) {
    // stage: thread tid owns c-row (hh*256 + tid), 32 k-cols, summed over lc
    {
      int c = tid;
      f32x4 s0 = {0,0,0,0}, s1 = {0,0,0,0}, s2 = {0,0,0,0}, s3 = {0,0,0,0};
      f32x4 s4 = {0,0,0,0}, s5 = {0,0,0,0}, s6 = {0,0,0,0}, s7 = {0,0,0,0};
      #pragma unroll
      for (int lcc = 0; lcc < 4; ++lcc) {
        const float* gp = Gp + (((size_t)n * 4 + lcc) * 512 + hh * 256 + c) * 256 + h * HK;
        s0 += *(const f32x4*)&gp[0];  s1 += *(const f32x4*)&gp[4];
        s2 += *(const f32x4*)&gp[8];  s3 += *(const f32x4*)&gp[12];
        s4 += *(const f32x4*)&gp[16]; s5 += *(const f32x4*)&gp[20];
        s6 += *(const f32x4*)&gp[24]; s7 += *(const f32x4*)&gp[28];
      }
      *(f32x4*)&Gs[c][0]  = s0; *(f32x4*)&Gs[c][4]  = s1;
      *(f32x4*)&Gs[c][8]  = s2; *(f32x4*)&Gs[c][12] = s3;
      *(f32x4*)&Gs[c][16] = s4; *(f32x4*)&Gs[c][20] = s5;
      *(f32x4*)&Gs[c][24] = s6; *(f32x4*)&Gs[c][28] = s7;
    }
    __syncthreads();
    const float* wvrow = Wv + (size_t)(h * HV + v) * C_IN + hh * 256;
    for (int c = 0; c < 256; ++c) {
      float w = wvrow[c];
      #pragma unroll
      for (int j = 0; j < 8; ++j) a[j] += w * Gs[c][kb + j];
    }
    __syncthreads();
  }

  float bvv = bv[h * HV + v];
  #pragma unroll
  for (int j = 0; j < 8; ++j) ctx[v][kb + j] = a[j] + bvv;
  __syncthreads();

  // We fold
  const int k  = tid & 31;
  const int og = tid >> 5;
  for (int j = 0; j < 64; ++j) {
    int o = og * 64 + j;
    const float* we = We + (size_t)o * VC + h * HV;
    float s = 0.f;
    #pragma unroll
    for (int vv = 0; vv < 64; ++vv) s += we[vv] * ctx[vv][k];
    Mbuf[((size_t)n * 512 + o) * KC + h * HK + k] = f2bf(s);
  }
}

// ---------------------------------------------------------------------------
// Kernel 5: out = x + be + M @ q_smT via MFMA (proven).
// ---------------------------------------------------------------------------
#define BM 128
#define BN 128
#define BK 32

__global__ __launch_bounds__(256) void k_final_mfma(
    const ushort* __restrict__ Mb,   // [n][512][256] bf16
    const ushort* __restrict__ qT,   // [n][4096][256] bf16
    const float* __restrict__ x,
    const float* __restrict__ be,
    float* __restrict__ out)
{
  const int n  = blockIdx.z;
  const int oy = blockIdx.y;   // 4
  const int lx = blockIdx.x;   // 32
  const int tid  = threadIdx.x;
  const int wave = tid >> 6, lane = tid & 63;
  const int wr = wave >> 1, wc = wave & 1;

  __shared__ __align__(16) char smem[32768 + 17408];

  f32x4 acc[4][4] = {};

  const ushort* gA = Mb + ((size_t)n * 512 + oy * BM) * KC;
  const ushort* gB = qT + ((size_t)n * L + lx * BN) * KC;

  const int r0 = wave * 32;
  const int lrow = lane >> 2;

  #define FSTAGE(buf, k0)                                                        \
    {                                                                            \
      ushort* As_ = (ushort*)(smem + (buf) * 16384);                             \
      ushort* Bs_ = (ushort*)(smem + (buf) * 16384 + 8192);                      \
      _Pragma("unroll")                                                          \
      for (int i_ = 0; i_ < 2; ++i_) {                                           \
        int row_ = r0 + i_ * 16 + lrow;                                          \
        int ss_ = (lane & 3) ^ ((row_ >> 1) & 3);                                \
        __builtin_amdgcn_global_load_lds(                                        \
            (const __attribute__((address_space(1))) uint32_t*)(gA + (size_t)row_ * KC + (k0) + ss_ * 8), \
            (__attribute__((address_space(3))) uint32_t*)(As_ + (r0 + i_ * 16) * BK), \
            16, 0, 0);                                                           \
        __builtin_amdgcn_global_load_lds(                                        \
            (const __attribute__((address_space(1))) uint32_t*)(gB + (size_t)row_ * KC + (k0) + ss_ * 8), \
            (__attribute__((address_space(3))) uint32_t*)(Bs_ + (r0 + i_ * 16) * BK), \
            16, 0, 0);                                                           \
      }                                                                          \
    }

  FSTAGE(0, 0)
  __syncthreads();

  const int nt = KC / BK;   // 8
  for (int t = 0; t < nt; ++t) {
    if (t < nt - 1) FSTAGE((t + 1) & 1, (t + 1) * BK)
    ushort* As = (ushort*)(smem + (t & 1) * 16384);
    ushort* Bs = (ushort*)(smem + (t & 1) * 16384 + 8192);
    s16x8 af[4], bfr[4];
    #pragma unroll
    for (int m = 0; m < 4; ++m) {
      int row = wr * 64 + m * 16 + (lane & 15);
      int slot = (lane >> 4) ^ ((row >> 1) & 3);
      af[m] = *(const s16x8*)&As[row * BK + slot * 8];
    }
    #pragma unroll
    for (int nn = 0; nn < 4; ++nn) {
      int row = wc * 64 + nn * 16 + (lane & 15);
      int slot = (lane >> 4) ^ ((row >> 1) & 3);
      bfr[nn] = *(const s16x8*)&Bs[row * BK + slot * 8];
    }
    __builtin_amdgcn_s_setprio(1);
    #pragma unroll
    for (int m = 0; m < 4; ++m)
      #pragma unroll
      for (int nn = 0; nn < 4; ++nn)
        acc[m][nn] = __builtin_amdgcn_mfma_f32_16x16x32_bf16(af[m], bfr[nn], acc[m][nn], 0, 0, 0);
    __builtin_amdgcn_s_setprio(0);
    __syncthreads();
  }
  #undef FSTAGE

  float* ep = (float*)(smem + 32768) + wave * (16 * 68);
  const int erow = lane >> 4;
  const int ecol = lane & 15;
  const float* bias = be + oy * BM + wr * 64;
  const float* xp = x + ((size_t)n * 512 + oy * BM + wr * 64) * L
                  + (size_t)lx * BN + wc * 64;
  float* op = out + ((size_t)n * 512 + oy * BM + wr * 64) * L
            + (size_t)lx * BN + wc * 64;
  #pragma unroll
  for (int m = 0; m < 4; ++m) {
    #pragma unroll
    for (int nn = 0; nn < 4; ++nn)
      #pragma unroll
      for (int r = 0; r < 4; ++r)
        ep[(erow * 4 + r) * 68 + nn * 16 + ecol] = acc[m][nn][r];
    #pragma unroll
    for (int p = 0; p < 4; ++p) {
      int row = p * 4 + erow;
      f32x4 v = *(const f32x4*)&ep[row * 68 + ecol * 4];
      float bo = bias[m * 16 + row];
      f32x4 xv = *(const f32x4*)&xp[(size_t)(m * 16 + row) * L + ecol * 4];
      v = v + xv + bo;
      *(f32x4*)&op[(size_t)(m * 16 + row) * L + ecol * 4] = v;
    }
  }
}

// ---------------------------------------------------------------------------
extern "C" void kernel_launch(void* const* d_in, const int* in_sizes, int n_in,
                              void* d_out, int out_size, void* d_ws, size_t ws_size,
                              hipStream_t stream)
{
  const float* x  = (const float*)d_in[0];
  const float* Wk = (const float*)d_in[1];
  const float* bk = (const float*)d_in[2];
  const float* Wq = (const float*)d_in[3];
  const float* bq = (const float*)d_in[4];
  const float* Wv = (const float*)d_in[5];
  const float* bv = (const float*)d_in[6];
  const float* We = (const float*)d_in[7];
  const float* be = (const float*)d_in[8];
  float* out = (float*)d_out;

  char* ws = (char*)d_ws;
  size_t off = 0;
  ushort* Kbuf = (ushort*)(ws + off); off += (size_t)N_BATCH * 256 * L * 2;        // 33.6 MB
  ushort* Ksm  = (ushort*)(ws + off); off += (size_t)N_BATCH * 256 * L * 2;        // 33.6 MB
  ushort* xT   = (ushort*)(ws + off); off += (size_t)N_BATCH * L * C_IN * 2;       // 67.1 MB
  ushort* Wb   = (ushort*)(ws + off); off += (size_t)512 * C_IN * 2;               // 0.5 MB
  float*  bb   = (float*)(ws + off);  off += (size_t)512 * 4;
  ushort* qT   = (ushort*)(ws + off); off += (size_t)N_BATCH * L * KC * 2;         // 33.6 MB
  float*  Gp   = (float*)(ws + off);  off += (size_t)N_BATCH * 4 * 512 * 256 * 4;  // 33.6 MB
  ushort* Mbuf = (ushort*)(ws + off); off += (size_t)N_BATCH * 512 * KC * 2;       // 4.2 MB

  (void)hipFuncSetAttribute((const void*)k_kq_mfma,
                            hipFuncAttributeMaxDynamicSharedMemorySize, 131072);
  (void)hipFuncSetAttribute((const void*)k_G,
                            hipFuncAttributeMaxDynamicSharedMemorySize, 98304);

  k_prep_w<<<dim3(512), 256, 0, stream>>>(Wk, bk, Wq, bq, Wb, bb);
  k_prep_x<<<dim3(64, 8, N_BATCH), 256, 0, stream>>>(x, xT);
  k_kq_mfma<<<dim3(16, 2, N_BATCH), 512, 131072, stream>>>(Wb, xT, bb, Kbuf, qT);
  k_kstats2<<<dim3(KC, N_BATCH), 256, 0, stream>>>(Kbuf, Ksm);
  k_G<<<dim3(4, 4, N_BATCH), 512, 98304, stream>>>(x, Ksm, Gp);
  k_m2<<<dim3(NH, N_BATCH), 256, 0, stream>>>(Gp, Wv, bv, We, Mbuf);
  k_final_mfma<<<dim3(32, 4, N_BATCH), 256, 0, stream>>>(Mbuf, qT, x, be, out);
}

// Round 11
// 265.703 us; speedup vs baseline: 1.1648x; 1.0971x over previous
//
#include <hip/hip_runtime.h>
#include <cstddef>
#include <cstdint>

#define N_BATCH 16
#define C_IN    512
#define L       4096
#define KC      256
#define VC      512
#define NH      8
#define HK      32   // KC/NH
#define HV      64   // VC/NH

using f32x4 = __attribute__((ext_vector_type(4))) float;
using s16x8 = __attribute__((ext_vector_type(8))) short;

// round-to-nearest-even fp32 -> bf16 bits
static __device__ inline ushort f2bf(float f) {
  uint32_t u = __float_as_uint(f);
  uint32_t r = (u + 0x7FFFu + ((u >> 16) & 1u)) >> 16;
  return (ushort)r;
}
static __device__ inline float bf2f(ushort u) {
  return __uint_as_float((uint32_t)u << 16);
}

// ---------------------------------------------------------------------------
// Prep 1: bf16 weight matrix Wb[512][512] (rows 0..255 K, 256..511 Q) + bias
// ---------------------------------------------------------------------------
__global__ __launch_bounds__(256) void k_prep_w(
    const float* __restrict__ Wk, const float* __restrict__ bk,
    const float* __restrict__ Wq, const float* __restrict__ bq,
    ushort* __restrict__ Wb, float* __restrict__ bb)
{
  const int o = blockIdx.x;          // 512
  const float* src; const float* bsrc; int oo;
  if (o < 256) { src = Wk + (size_t)o * C_IN;         bsrc = bk; oo = o; }
  else         { src = Wq + (size_t)(o - 256) * C_IN; bsrc = bq; oo = o - 256; }
  const int t = threadIdx.x;
  Wb[(size_t)o * C_IN + t * 2]     = f2bf(src[t * 2]);
  Wb[(size_t)o * C_IN + t * 2 + 1] = f2bf(src[t * 2 + 1]);
  if (t == 0) bb[o] = bsrc[oo];
}

// ---------------------------------------------------------------------------
// Prep 2: transpose+cast x (n,512,4096) f32 -> xT (n,4096,512) bf16
// ---------------------------------------------------------------------------
__global__ __launch_bounds__(256) void k_prep_x(const float* __restrict__ x,
                                                ushort* __restrict__ xT)
{
  __shared__ float t[64][65];
  const int n = blockIdx.z, cy = blockIdx.y, lx = blockIdx.x;
  const float* xp = x + ((size_t)n * C_IN + cy * 64) * L + (size_t)lx * 64;
  const int l4 = (threadIdx.x & 15) * 4;
  const int c0 = threadIdx.x >> 4;
  #pragma unroll
  for (int i = 0; i < 4; ++i) {
    int cc = c0 + i * 16;
    f32x4 v = *(const f32x4*)&xp[(size_t)cc * L + l4];
    t[cc][l4]     = v[0];
    t[cc][l4 + 1] = v[1];
    t[cc][l4 + 2] = v[2];
    t[cc][l4 + 3] = v[3];
  }
  __syncthreads();
  ushort* op = xT + ((size_t)n * L + lx * 64) * C_IN + cy * 64;
  const int cp = (threadIdx.x & 15) * 4;
  const int l0 = threadIdx.x >> 4;
  #pragma unroll
  for (int i = 0; i < 4; ++i) {
    int lr = l0 + i * 16;
    uint2 pk;
    pk.x = (uint32_t)f2bf(t[cp][lr])     | ((uint32_t)f2bf(t[cp + 1][lr]) << 16);
    pk.y = (uint32_t)f2bf(t[cp + 2][lr]) | ((uint32_t)f2bf(t[cp + 3][lr]) << 16);
    *(uint2*)(op + (size_t)lr * C_IN + cp) = pk;
  }
}

// ---------------------------------------------------------------------------
// Kernel 1: [K;Q] = Wb @ x + bias, bf16 MFMA, 256x256 tile, BK=64, 8 waves.
// Round-6 proven 2-phase dbuf structure.  oy=0 -> Kbuf; oy=1 -> fused
// channel softmax -> qT.
// ---------------------------------------------------------------------------
#define QBM 256
#define QBN 256
#define QBK 64

__global__ __launch_bounds__(512) void k_kq_mfma(
    const ushort* __restrict__ Wb,   // [512][512] bf16
    const ushort* __restrict__ xT,   // [n][4096][512] bf16
    const float* __restrict__ bb,    // [512]
    ushort* __restrict__ Kbuf,       // [n][256][4096] bf16
    ushort* __restrict__ qT)         // [n][4096][256] bf16 (normalized Q^T)
{
  extern __shared__ __align__(16) char smem[];
  const int n  = blockIdx.z;
  const int oy = blockIdx.y;   // 0 = K rows, 1 = Q rows
  const int lx = blockIdx.x;   // 16 col tiles of 256
  const int tid  = threadIdx.x;
  const int wave = tid >> 6, lane = tid & 63;
  const int wr = wave >> 2, wc = wave & 3;   // 2 x 4

  f32x4 acc[8][4] = {};

  const ushort* gA = Wb + (size_t)(oy * QBM) * C_IN;
  const ushort* gB = xT + ((size_t)n * L + lx * QBN) * C_IN;

  const int srow = lane >> 3;
  const int sslotbase = lane & 7;

  #define QSTAGE(buf, k0)                                                        \
    {                                                                            \
      ushort* As_ = (ushort*)(smem + (buf) * 65536);                             \
      ushort* Bs_ = (ushort*)(smem + (buf) * 65536 + 32768);                     \
      _Pragma("unroll")                                                          \
      for (int i_ = 0; i_ < 4; ++i_) {                                           \
        int rbase_ = wave * 32 + i_ * 8;                                         \
        int row_ = rbase_ + srow;                                                \
        int ss_ = sslotbase ^ (row_ & 7);                                        \
        __builtin_amdgcn_global_load_lds(                                        \
            (const __attribute__((address_space(1))) uint32_t*)(gA + (size_t)row_ * C_IN + (k0) + ss_ * 8), \
            (__attribute__((address_space(3))) uint32_t*)(As_ + rbase_ * QBK),   \
            16, 0, 0);                                                           \
        __builtin_amdgcn_global_load_lds(                                        \
            (const __attribute__((address_space(1))) uint32_t*)(gB + (size_t)row_ * C_IN + (k0) + ss_ * 8), \
            (__attribute__((address_space(3))) uint32_t*)(Bs_ + rbase_ * QBK),   \
            16, 0, 0);                                                           \
      }                                                                          \
    }

  QSTAGE(0, 0)
  __syncthreads();

  const int nt = C_IN / QBK;   // 8
  for (int t = 0; t < nt; ++t) {
    if (t < nt - 1) QSTAGE((t + 1) & 1, (t + 1) * QBK)
    ushort* As = (ushort*)(smem + (t & 1) * 65536);
    ushort* Bs = (ushort*)(smem + (t & 1) * 65536 + 32768);
    __builtin_amdgcn_s_setprio(1);
    #pragma unroll
    for (int ks = 0; ks < 2; ++ks) {
      s16x8 af[8], bfr[4];
      #pragma unroll
      for (int m = 0; m < 8; ++m) {
        int row = wr * 128 + m * 16 + (lane & 15);
        int slot = (ks * 4 + (lane >> 4)) ^ (row & 7);
        af[m] = *(const s16x8*)&As[row * QBK + slot * 8];
      }
      #pragma unroll
      for (int nn = 0; nn < 4; ++nn) {
        int row = wc * 64 + nn * 16 + (lane & 15);
        int slot = (ks * 4 + (lane >> 4)) ^ (row & 7);
        bfr[nn] = *(const s16x8*)&Bs[row * QBK + slot * 8];
      }
      #pragma unroll
      for (int m = 0; m < 8; ++m)
        #pragma unroll
        for (int nn = 0; nn < 4; ++nn)
          acc[m][nn] = __builtin_amdgcn_mfma_f32_16x16x32_bf16(af[m], bfr[nn], acc[m][nn], 0, 0, 0);
    }
    __builtin_amdgcn_s_setprio(0);
    __syncthreads();
  }
  #undef QSTAGE

  if (oy == 0) {
    float* ep = (float*)smem + wave * (16 * 68);
    const int erow = lane >> 4;
    const int ecol = lane & 15;
    const float* bias = bb + wr * 128;
    ushort* outp = Kbuf + ((size_t)n * 256 + wr * 128) * L
                 + (size_t)lx * QBN + wc * 64;
    #pragma unroll
    for (int m = 0; m < 8; ++m) {
      #pragma unroll
      for (int nn = 0; nn < 4; ++nn)
        #pragma unroll
        for (int r = 0; r < 4; ++r)
          ep[(erow * 4 + r) * 68 + nn * 16 + ecol] = acc[m][nn][r];
      #pragma unroll
      for (int p = 0; p < 4; ++p) {
        int row = p * 4 + erow;
        f32x4 v = *(const f32x4*)&ep[row * 68 + ecol * 4];
        float bo = bias[m * 16 + row];
        uint2 pk;
        pk.x = (uint32_t)f2bf(v[0] + bo) | ((uint32_t)f2bf(v[1] + bo) << 16);
        pk.y = (uint32_t)f2bf(v[2] + bo) | ((uint32_t)f2bf(v[3] + bo) << 16);
        *(uint2*)&outp[(size_t)(m * 16 + row) * L + ecol * 4] = pk;
      }
    }
  } else {
    const float* bias = bb + 256 + wr * 128;
    ushort* qbase = qT + (size_t)n * L * KC;
    const int g4 = (lane >> 4) * 4;
    #pragma unroll
    for (int hp = 0; hp < 4; ++hp) {
      const int m0 = 2 * hp, m1 = 2 * hp + 1;
      const float b0_0 = bias[m0 * 16 + g4 + 0], b0_1 = bias[m0 * 16 + g4 + 1];
      const float b0_2 = bias[m0 * 16 + g4 + 2], b0_3 = bias[m0 * 16 + g4 + 3];
      const float b1_0 = bias[m1 * 16 + g4 + 0], b1_1 = bias[m1 * 16 + g4 + 1];
      const float b1_2 = bias[m1 * 16 + g4 + 2], b1_3 = bias[m1 * 16 + g4 + 3];
      #pragma unroll
      for (int nn = 0; nn < 4; ++nn) {
        float v0[4], v1[4];
        v0[0] = acc[m0][nn][0] + b0_0; v0[1] = acc[m0][nn][1] + b0_1;
        v0[2] = acc[m0][nn][2] + b0_2; v0[3] = acc[m0][nn][3] + b0_3;
        v1[0] = acc[m1][nn][0] + b1_0; v1[1] = acc[m1][nn][1] + b1_1;
        v1[2] = acc[m1][nn][2] + b1_2; v1[3] = acc[m1][nn][3] + b1_3;
        float mx = fmaxf(fmaxf(fmaxf(v0[0], v0[1]), fmaxf(v0[2], v0[3])),
                         fmaxf(fmaxf(v1[0], v1[1]), fmaxf(v1[2], v1[3])));
        mx = fmaxf(mx, __shfl_xor(mx, 16));
        mx = fmaxf(mx, __shfl_xor(mx, 32));
        float e0[4], e1[4];
        float s = 0.f;
        #pragma unroll
        for (int r = 0; r < 4; ++r) { e0[r] = __expf(v0[r] - mx); s += e0[r]; }
        #pragma unroll
        for (int r = 0; r < 4; ++r) { e1[r] = __expf(v1[r] - mx); s += e1[r]; }
        s += __shfl_xor(s, 16);
        s += __shfl_xor(s, 32);
        float inv = 1.0f / s;
        int l = lx * QBN + wc * 64 + nn * 16 + (lane & 15);
        ushort* dst = qbase + (size_t)l * KC + wr * 128;
        uint2 p0, p1;
        p0.x = (uint32_t)f2bf(e0[0] * inv) | ((uint32_t)f2bf(e0[1] * inv) << 16);
        p0.y = (uint32_t)f2bf(e0[2] * inv) | ((uint32_t)f2bf(e0[3] * inv) << 16);
        p1.x = (uint32_t)f2bf(e1[0] * inv) | ((uint32_t)f2bf(e1[1] * inv) << 16);
        p1.y = (uint32_t)f2bf(e1[2] * inv) | ((uint32_t)f2bf(e1[3] * inv) << 16);
        *(uint2*)&dst[m0 * 16 + g4] = p0;
        *(uint2*)&dst[m1 * 16 + g4] = p1;
      }
    }
  }
}

// ---------------------------------------------------------------------------
// Reductions
// ---------------------------------------------------------------------------
__device__ inline float blockReduceMax(float v, float* red) {
  #pragma unroll
  for (int off = 32; off > 0; off >>= 1)
    v = fmaxf(v, __shfl_down(v, off, 64));
  int tid = threadIdx.x;
  if ((tid & 63) == 0) red[tid >> 6] = v;
  __syncthreads();
  return fmaxf(fmaxf(red[0], red[1]), fmaxf(red[2], red[3]));
}
__device__ inline float blockReduceSum(float v, float* red) {
  #pragma unroll
  for (int off = 32; off > 0; off >>= 1)
    v += __shfl_down(v, off, 64);
  int tid = threadIdx.x;
  if ((tid & 63) == 0) red[tid >> 6] = v;
  __syncthreads();
  return red[0] + red[1] + red[2] + red[3];
}

// ---------------------------------------------------------------------------
// Kernel 2: K softmax over L per (n,row); writes normalized Ksm bf16.
// ---------------------------------------------------------------------------
__global__ __launch_bounds__(256) void k_kstats2(const ushort* __restrict__ Kbuf,
                                                 ushort* __restrict__ Ksm)
{
  const int r = blockIdx.x;
  const int n = blockIdx.y;
  const ushort* row = Kbuf + ((size_t)n * 256 + r) * L;
  ushort* orow = Ksm + ((size_t)n * 256 + r) * L;
  __shared__ float red1[4];
  __shared__ float red2[4];
  const int tid = threadIdx.x;
  s16x8 a = *(const s16x8*)(row + tid * 16);
  s16x8 b = *(const s16x8*)(row + tid * 16 + 8);
  float v[16];
  #pragma unroll
  for (int j = 0; j < 8; ++j) { v[j] = bf2f((ushort)a[j]); v[8 + j] = bf2f((ushort)b[j]); }
  float m = -3.0e38f;
  #pragma unroll
  for (int j = 0; j < 16; ++j) m = fmaxf(m, v[j]);
  m = blockReduceMax(m, red1);
  float s = 0.f;
  #pragma unroll
  for (int j = 0; j < 16; ++j) s += __expf(v[j] - m);
  s = blockReduceSum(s, red2);
  float inv = 1.0f / s;
  s16x8 w0, w1;
  #pragma unroll
  for (int j = 0; j < 8; ++j) {
    w0[j] = (short)f2bf(__expf(v[j] - m) * inv);
    w1[j] = (short)f2bf(__expf(v[8 + j] - m) * inv);
  }
  *(s16x8*)(orow + tid * 16)     = w0;
  *(s16x8*)(orow + tid * 16 + 8) = w1;
}

// ---------------------------------------------------------------------------
// Kernel 3: G[c][k] = sum_l x[c,l] * Ksm[k,l]  (per n, partial over l-chunk).
// A = x f32 reg-staged; B = Ksm via global_load_lds.  M=128(c), N=256(k),
// BK=64, 8 waves, 2-phase dbuf.  Gp[n][4][512][256] f32 partials.
// ---------------------------------------------------------------------------
#define GBK 64

__global__ __launch_bounds__(512) void k_G(
    const float* __restrict__ x,     // [n][512][4096] f32
    const ushort* __restrict__ Ksm,  // [n][256][4096] bf16
    float* __restrict__ Gp)          // [n][4][512][256] f32
{
  extern __shared__ __align__(16) char smem[];
  const int cm = blockIdx.x;   // 4 c-tiles of 128
  const int lc = blockIdx.y;   // 4 l-chunks of 1024
  const int n  = blockIdx.z;
  const int tid  = threadIdx.x;
  const int wave = tid >> 6, lane = tid & 63;
  const int wr = wave >> 2, wc = wave & 3;   // 2 x 4

  f32x4 acc[4][4] = {};

  const float*  gx = x   + ((size_t)n * C_IN + cm * 128) * L + lc * 1024;
  const ushort* gK = Ksm + (size_t)n * 256 * L + lc * 1024;

  const int arow = tid >> 2;          // 0..127
  const int aseg = (tid & 3) * 2;

  #define GSTAGEB(buf, k0)                                                       \
    {                                                                            \
      ushort* Bs_ = (ushort*)(smem + (buf) * 49152 + 16384);                     \
      _Pragma("unroll")                                                          \
      for (int i_ = 0; i_ < 4; ++i_) {                                           \
        int rbase_ = wave * 32 + i_ * 8;                                         \
        int row_ = rbase_ + (lane >> 3);                                         \
        int ss_ = (lane & 7) ^ (row_ & 7);                                       \
        __builtin_amdgcn_global_load_lds(                                        \
            (const __attribute__((address_space(1))) uint32_t*)(gK + (size_t)row_ * L + (k0) + ss_ * 8), \
            (__attribute__((address_space(3))) uint32_t*)(Bs_ + rbase_ * GBK),   \
            16, 0, 0);                                                           \
      }                                                                          \
    }

  #define GLOADA(k0)                                                             \
    a0 = *(const f32x4*)&gx[(size_t)arow * L + (k0) + aseg * 8];                 \
    a1 = *(const f32x4*)&gx[(size_t)arow * L + (k0) + aseg * 8 + 4];             \
    a2 = *(const f32x4*)&gx[(size_t)arow * L + (k0) + aseg * 8 + 8];             \
    a3 = *(const f32x4*)&gx[(size_t)arow * L + (k0) + aseg * 8 + 12];

  #define GWRITEA(buf)                                                           \
    {                                                                            \
      ushort* As_ = (ushort*)(smem + (buf) * 49152);                             \
      s16x8 w0_, w1_;                                                            \
      _Pragma("unroll")                                                          \
      for (int j_ = 0; j_ < 4; ++j_) {                                           \
        w0_[j_]     = (short)f2bf(a0[j_]);                                       \
        w0_[j_ + 4] = (short)f2bf(a1[j_]);                                       \
        w1_[j_]     = (short)f2bf(a2[j_]);                                       \
        w1_[j_ + 4] = (short)f2bf(a3[j_]);                                       \
      }                                                                          \
      *(s16x8*)&As_[arow * GBK + ((aseg)     ^ (arow & 7)) * 8] = w0_;           \
      *(s16x8*)&As_[arow * GBK + ((aseg + 1) ^ (arow & 7)) * 8] = w1_;           \
    }

  f32x4 a0, a1, a2, a3;

  GLOADA(0)
  GSTAGEB(0, 0)
  GWRITEA(0)
  __syncthreads();

  const int nt = 1024 / GBK;   // 16
  for (int t = 0; t < nt; ++t) {
    const int cb = t & 1, nb = cb ^ 1;
    if (t < nt - 1) {
      GLOADA((t + 1) * GBK)
      GSTAGEB(nb, (t + 1) * GBK)
    }
    ushort* As = (ushort*)(smem + cb * 49152);
    ushort* Bs = (ushort*)(smem + cb * 49152 + 16384);
    __builtin_amdgcn_s_setprio(1);
    #pragma unroll
    for (int ks = 0; ks < 2; ++ks) {
      s16x8 af[4], bfr[4];
      #pragma unroll
      for (int m = 0; m < 4; ++m) {
        int row = wr * 64 + m * 16 + (lane & 15);
        int slot = (ks * 4 + (lane >> 4)) ^ (row & 7);
        af[m] = *(const s16x8*)&As[row * GBK + slot * 8];
      }
      #pragma unroll
      for (int nn = 0; nn < 4; ++nn) {
        int row = wc * 64 + nn * 16 + (lane & 15);
        int slot = (ks * 4 + (lane >> 4)) ^ (row & 7);
        bfr[nn] = *(const s16x8*)&Bs[row * GBK + slot * 8];
      }
      #pragma unroll
      for (int m = 0; m < 4; ++m)
        #pragma unroll
        for (int nn = 0; nn < 4; ++nn)
          acc[m][nn] = __builtin_amdgcn_mfma_f32_16x16x32_bf16(af[m], bfr[nn], acc[m][nn], 0, 0, 0);
    }
    __builtin_amdgcn_s_setprio(0);
    if (t < nt - 1) GWRITEA(nb)
    __syncthreads();
  }
  #undef GSTAGEB
  #undef GLOADA
  #undef GWRITEA

  float* ep = (float*)smem + wave * (16 * 68);
  const int erow = lane >> 4;
  const int ecol = lane & 15;
  float* op = Gp + (((size_t)n * 4 + lc) * 512 + cm * 128 + wr * 64) * 256 + wc * 64;
  #pragma unroll
  for (int m = 0; m < 4; ++m) {
    #pragma unroll
    for (int nn = 0; nn < 4; ++nn)
      #pragma unroll
      for (int r = 0; r < 4; ++r)
        ep[(erow * 4 + r) * 68 + nn * 16 + ecol] = acc[m][nn][r];
    #pragma unroll
    for (int p = 0; p < 4; ++p) {
      int row16 = p * 4 + erow;
      f32x4 v = *(const f32x4*)&ep[row16 * 68 + ecol * 4];
      *(f32x4*)&op[(size_t)(m * 16 + row16) * 256 + ecol * 4] = v;
    }
  }
}

// ---------------------------------------------------------------------------
// Kernel 4a: F[h][o][c] = sum_v We[o][h*64+v] * Wv[h*64+v][c]  (bf16)
//            Fb[h][o]   = sum_v We[o][h*64+v] * bv[h*64+v]     (f32)
// grid (8 h, 32 og of 16 o), 256 threads (each: 2 c, 16 o).
// ---------------------------------------------------------------------------
__global__ __launch_bounds__(256) void k_F(
    const float* __restrict__ Wv, const float* __restrict__ bv,
    const float* __restrict__ We,
    ushort* __restrict__ F, float* __restrict__ Fb)
{
  const int h  = blockIdx.x;   // 8
  const int og = blockIdx.y;   // 32
  const int tid = threadIdx.x;
  __shared__ float Ws[16][64];
  #pragma unroll
  for (int i = 0; i < 4; ++i) {
    int e = tid + i * 256;
    int o = e >> 6, v = e & 63;
    Ws[o][v] = We[(size_t)(og * 16 + o) * VC + h * 64 + v];
  }
  __syncthreads();
  const int c2 = tid * 2;
  float acc[16][2] = {};
  for (int v = 0; v < 64; ++v) {
    float2 w = *(const float2*)&Wv[(size_t)(h * 64 + v) * C_IN + c2];
    #pragma unroll
    for (int o = 0; o < 16; ++o) {
      acc[o][0] += Ws[o][v] * w.x;
      acc[o][1] += Ws[o][v] * w.y;
    }
  }
  ushort* Fh = F + ((size_t)h * 512 + og * 16) * C_IN;
  #pragma unroll
  for (int o = 0; o < 16; ++o) {
    uint32_t pk = (uint32_t)f2bf(acc[o][0]) | ((uint32_t)f2bf(acc[o][1]) << 16);
    *(uint32_t*)&Fh[(size_t)o * C_IN + c2] = pk;
  }
  if (tid < 16) {
    float s = 0.f;
    for (int v = 0; v < 64; ++v) s += Ws[tid][v] * bv[h * 64 + v];
    Fb[h * 512 + og * 16 + tid] = s;
  }
}

// ---------------------------------------------------------------------------
// Kernel 4b: M[o][h*32+k] = sum_c F_h[o][c] * G[c][h*32+k] + Fb[h][o]  (bf16)
// grid (4 oy, 8 h, 16 n), 256 threads, 4 waves.  B = G^T slice (32k x 512c)
// summed over 4 lc partials into resident swizzled LDS; A = F_h via
// global_load_lds double-buffer (BK=64); MFMA 16x16x32.
// ---------------------------------------------------------------------------
__global__ __launch_bounds__(256) void k_M(
    const float* __restrict__ Gp,   // [n][4][512][256] f32
    const ushort* __restrict__ F,   // [8][512][512] bf16
    const float* __restrict__ Fb,   // [8][512] f32
    ushort* __restrict__ Mbuf)      // [n][512][256] bf16
{
  const int oy = blockIdx.x;   // 4
  const int h  = blockIdx.y;   // 8
  const int n  = blockIdx.z;   // 16
  const int tid = threadIdx.x, wave = tid >> 6, lane = tid & 63;

  __shared__ __align__(16) char smem[32768 + 32768 + 9216];
  ushort* GTs = (ushort*)smem;                  // [32][512] swizzled, 32 KB

  // ---- B-prep: GT[k][c] = sum_lc Gp[n][lc][c][h*32+k], swizzled bf16 ----
  #pragma unroll
  for (int i = 0; i < 16; ++i) {
    int e = tid + i * 256;              // 4096 = 512 c x 8 kq
    int c = e >> 3, kq = e & 7;
    int k = kq * 4;
    const float* gp = Gp + ((size_t)n * 4 * 512 + c) * 256 + h * HK + k;
    f32x4 s = *(const f32x4*)gp;
    s += *(const f32x4*)(gp + (size_t)512 * 256);
    s += *(const f32x4*)(gp + (size_t)2 * 512 * 256);
    s += *(const f32x4*)(gp + (size_t)3 * 512 * 256);
    #pragma unroll
    for (int j = 0; j < 4; ++j) {
      int kk = k + j;
      GTs[kk * 512 + (((c >> 3) ^ (kk & 7)) * 8) + (c & 7)] = f2bf(s[j]);
    }
  }

  const ushort* gA = F + ((size_t)h * 512 + oy * 128) * C_IN;

  #define MSTAGE(buf, k0)                                                        \
    {                                                                            \
      ushort* As_ = (ushort*)(smem + 32768 + (buf) * 16384);                     \
      _Pragma("unroll")                                                          \
      for (int i_ = 0; i_ < 4; ++i_) {                                           \
        int rbase_ = wave * 32 + i_ * 8;                                         \
        int row_ = rbase_ + (lane >> 3);                                         \
        int ss_ = (lane & 7) ^ (row_ & 7);                                       \
        __builtin_amdgcn_global_load_lds(                                        \
            (const __attribute__((address_space(1))) uint32_t*)(gA + (size_t)row_ * C_IN + (k0) + ss_ * 8), \
            (__attribute__((address_space(3))) uint32_t*)(As_ + rbase_ * 64),    \
            16, 0, 0);                                                           \
      }                                                                          \
    }

  f32x4 acc[2][2] = {};

  MSTAGE(0, 0)
  __syncthreads();   // covers GT writes + stage 0

  const int nt = C_IN / 64;   // 8
  for (int t = 0; t < nt; ++t) {
    if (t < nt - 1) MSTAGE((t + 1) & 1, (t + 1) * 64)
    ushort* As = (ushort*)(smem + 32768 + (t & 1) * 16384);
    __builtin_amdgcn_s_setprio(1);
    #pragma unroll
    for (int ks = 0; ks < 2; ++ks) {
      s16x8 af[2], bfr[2];
      #pragma unroll
      for (int m = 0; m < 2; ++m) {
        int row = wave * 32 + m * 16 + (lane & 15);
        int slot = (ks * 4 + (lane >> 4)) ^ (row & 7);
        af[m] = *(const s16x8*)&As[row * 64 + slot * 8];
      }
      #pragma unroll
      for (int nf = 0; nf < 2; ++nf) {
        int kr = nf * 16 + (lane & 15);
        int slot = (t * 8 + ks * 4 + (lane >> 4)) ^ (kr & 7);
        bfr[nf] = *(const s16x8*)&GTs[kr * 512 + slot * 8];
      }
      #pragma unroll
      for (int m = 0; m < 2; ++m)
        #pragma unroll
        for (int nf = 0; nf < 2; ++nf)
          acc[m][nf] = __builtin_amdgcn_mfma_f32_16x16x32_bf16(af[m], bfr[nf], acc[m][nf], 0, 0, 0);
    }
    __builtin_amdgcn_s_setprio(0);
    __syncthreads();
  }
  #undef MSTAGE

  // Epilogue: wave-private 16x36 f32 staging -> packed bf16 stores (+Fb).
  float* ep = (float*)(smem + 65536) + wave * (16 * 36);
  const int erow = lane >> 4;
  const int ecol = lane & 15;
  #pragma unroll
  for (int m = 0; m < 2; ++m) {
    #pragma unroll
    for (int nf = 0; nf < 2; ++nf)
      #pragma unroll
      for (int r = 0; r < 4; ++r)
        ep[(erow * 4 + r) * 36 + nf * 16 + ecol] = acc[m][nf][r];
    #pragma unroll
    for (int p = 0; p < 2; ++p) {
      int row16 = p * 8 + (lane >> 3);
      int c4 = (lane & 7) * 4;
      f32x4 v = *(const f32x4*)&ep[row16 * 36 + c4];
      int o = oy * 128 + wave * 32 + m * 16 + row16;
      float fb = Fb[h * 512 + o];
      uint2 pk;
      pk.x = (uint32_t)f2bf(v[0] + fb) | ((uint32_t)f2bf(v[1] + fb) << 16);
      pk.y = (uint32_t)f2bf(v[2] + fb) | ((uint32_t)f2bf(v[3] + fb) << 16);
      *(uint2*)&Mbuf[((size_t)n * 512 + o) * KC + h * HK + c4] = pk;
    }
  }
}

// ---------------------------------------------------------------------------
// Kernel 5: out = x + be + M @ q_smT via MFMA (proven).
// ---------------------------------------------------------------------------
#define BM 128
#define BN 128
#define BK 32

__global__ __launch_bounds__(256) void k_final_mfma(
    const ushort* __restrict__ Mb,   // [n][512][256] bf16
    const ushort* __restrict__ qT,   // [n][4096][256] bf16
    const float* __restrict__ x,
    const float* __restrict__ be,
    float* __restrict__ out)
{
  const int n  = blockIdx.z;
  const int oy = blockIdx.y;   // 4
  const int lx = blockIdx.x;   // 32
  const int tid  = threadIdx.x;
  const int wave = tid >> 6, lane = tid & 63;
  const int wr = wave >> 1, wc = wave & 1;

  __shared__ __align__(16) char smem[32768 + 17408];

  f32x4 acc[4][4] = {};

  const ushort* gA = Mb + ((size_t)n * 512 + oy * BM) * KC;
  const ushort* gB = qT + ((size_t)n * L + lx * BN) * KC;

  const int r0 = wave * 32;
  const int lrow = lane >> 2;

  #define FSTAGE(buf, k0)                                                        \
    {                                                                            \
      ushort* As_ = (ushort*)(smem + (buf) * 16384);                             \
      ushort* Bs_ = (ushort*)(smem + (buf) * 16384 + 8192);                      \
      _Pragma("unroll")                                                          \
      for (int i_ = 0; i_ < 2; ++i_) {                                           \
        int row_ = r0 + i_ * 16 + lrow;                                          \
        int ss_ = (lane & 3) ^ ((row_ >> 1) & 3);                                \
        __builtin_amdgcn_global_load_lds(                                        \
            (const __attribute__((address_space(1))) uint32_t*)(gA + (size_t)row_ * KC + (k0) + ss_ * 8), \
            (__attribute__((address_space(3))) uint32_t*)(As_ + (r0 + i_ * 16) * BK), \
            16, 0, 0);                                                           \
        __builtin_amdgcn_global_load_lds(                                        \
            (const __attribute__((address_space(1))) uint32_t*)(gB + (size_t)row_ * KC + (k0) + ss_ * 8), \
            (__attribute__((address_space(3))) uint32_t*)(Bs_ + (r0 + i_ * 16) * BK), \
            16, 0, 0);                                                           \
      }                                                                          \
    }

  FSTAGE(0, 0)
  __syncthreads();

  const int nt = KC / BK;   // 8
  for (int t = 0; t < nt; ++t) {
    if (t < nt - 1) FSTAGE((t + 1) & 1, (t + 1) * BK)
    ushort* As = (ushort*)(smem + (t & 1) * 16384);
    ushort* Bs = (ushort*)(smem + (t & 1) * 16384 + 8192);
    s16x8 af[4], bfr[4];
    #pragma unroll
    for (int m = 0; m < 4; ++m) {
      int row = wr * 64 + m * 16 + (lane & 15);
      int slot = (lane >> 4) ^ ((row >> 1) & 3);
      af[m] = *(const s16x8*)&As[row * BK + slot * 8];
    }
    #pragma unroll
    for (int nn = 0; nn < 4; ++nn) {
      int row = wc * 64 + nn * 16 + (lane & 15);
      int slot = (lane >> 4) ^ ((row >> 1) & 3);
      bfr[nn] = *(const s16x8*)&Bs[row * BK + slot * 8];
    }
    __builtin_amdgcn_s_setprio(1);
    #pragma unroll
    for (int m = 0; m < 4; ++m)
      #pragma unroll
      for (int nn = 0; nn < 4; ++nn)
        acc[m][nn] = __builtin_amdgcn_mfma_f32_16x16x32_bf16(af[m], bfr[nn], acc[m][nn], 0, 0, 0);
    __builtin_amdgcn_s_setprio(0);
    __syncthreads();
  }
  #undef FSTAGE

  float* ep = (float*)(smem + 32768) + wave * (16 * 68);
  const int erow = lane >> 4;
  const int ecol = lane & 15;
  const float* bias = be + oy * BM + wr * 64;
  const float* xp = x + ((size_t)n * 512 + oy * BM + wr * 64) * L
                  + (size_t)lx * BN + wc * 64;
  float* op = out + ((size_t)n * 512 + oy * BM + wr * 64) * L
            + (size_t)lx * BN + wc * 64;
  #pragma unroll
  for (int m = 0; m < 4; ++m) {
    #pragma unroll
    for (int nn = 0; nn < 4; ++nn)
      #pragma unroll
      for (int r = 0; r < 4; ++r)
        ep[(erow * 4 + r) * 68 + nn * 16 + ecol] = acc[m][nn][r];
    #pragma unroll
    for (int p = 0; p < 4; ++p) {
      int row = p * 4 + erow;
      f32x4 v = *(const f32x4*)&ep[row * 68 + ecol * 4];
      float bo = bias[m * 16 + row];
      f32x4 xv = *(const f32x4*)&xp[(size_t)(m * 16 + row) * L + ecol * 4];
      v = v + xv + bo;
      *(f32x4*)&op[(size_t)(m * 16 + row) * L + ecol * 4] = v;
    }
  }
}

// ---------------------------------------------------------------------------
extern "C" void kernel_launch(void* const* d_in, const int* in_sizes, int n_in,
                              void* d_out, int out_size, void* d_ws, size_t ws_size,
                              hipStream_t stream)
{
  const float* x  = (const float*)d_in[0];
  const float* Wk = (const float*)d_in[1];
  const float* bk = (const float*)d_in[2];
  const float* Wq = (const float*)d_in[3];
  const float* bq = (const float*)d_in[4];
  const float* Wv = (const float*)d_in[5];
  const float* bv = (const float*)d_in[6];
  const float* We = (const float*)d_in[7];
  const float* be = (const float*)d_in[8];
  float* out = (float*)d_out;

  char* ws = (char*)d_ws;
  size_t off = 0;
  ushort* Kbuf = (ushort*)(ws + off); off += (size_t)N_BATCH * 256 * L * 2;        // 33.6 MB
  ushort* Ksm  = (ushort*)(ws + off); off += (size_t)N_BATCH * 256 * L * 2;        // 33.6 MB
  ushort* xT   = (ushort*)(ws + off); off += (size_t)N_BATCH * L * C_IN * 2;       // 67.1 MB
  ushort* Wb   = (ushort*)(ws + off); off += (size_t)512 * C_IN * 2;               // 0.5 MB
  float*  bb   = (float*)(ws + off);  off += (size_t)512 * 4;
  ushort* qT   = (ushort*)(ws + off); off += (size_t)N_BATCH * L * KC * 2;         // 33.6 MB
  float*  Gp   = (float*)(ws + off);  off += (size_t)N_BATCH * 4 * 512 * 256 * 4;  // 33.6 MB
  ushort* Fbuf = (ushort*)(ws + off); off += (size_t)NH * 512 * C_IN * 2;          // 4.2 MB
  float*  Fb   = (float*)(ws + off);  off += (size_t)NH * 512 * 4;
  ushort* Mbuf = (ushort*)(ws + off); off += (size_t)N_BATCH * 512 * KC * 2;       // 4.2 MB

  (void)hipFuncSetAttribute((const void*)k_kq_mfma,
                            hipFuncAttributeMaxDynamicSharedMemorySize, 131072);
  (void)hipFuncSetAttribute((const void*)k_G,
                            hipFuncAttributeMaxDynamicSharedMemorySize, 98304);

  k_prep_w<<<dim3(512), 256, 0, stream>>>(Wk, bk, Wq, bq, Wb, bb);
  k_F<<<dim3(NH, 32), 256, 0, stream>>>(Wv, bv, We, Fbuf, Fb);
  k_prep_x<<<dim3(64, 8, N_BATCH), 256, 0, stream>>>(x, xT);
  k_kq_mfma<<<dim3(16, 2, N_BATCH), 512, 131072, stream>>>(Wb, xT, bb, Kbuf, qT);
  k_kstats2<<<dim3(KC, N_BATCH), 256, 0, stream>>>(Kbuf, Ksm);
  k_G<<<dim3(4, 4, N_BATCH), 512, 98304, stream>>>(x, Ksm, Gp);
  k_M<<<dim3(4, NH, N_BATCH), 256, 0, stream>>>(Gp, Fbuf, Fb, Mbuf);
  k_final_mfma<<<dim3(32, 4, N_BATCH), 256, 0, stream>>>(Mbuf, qT, x, be, out);
}